// Round 1
// 371.626 us; speedup vs baseline: 1.0931x; 1.0931x over previous
//
#include <hip/hip_runtime.h>
#include <hip/hip_fp16.h>

#define NM 131072   // mol nodes
#define EM 524288   // mol edges
#define NG 4096     // graphs
#define DM 6        // mol in dim
#define NP 100000   // prot nodes
#define EP 1600000  // prot edges
#define DP 20       // prot in dim

static inline int cdiv(int a, int b){ return (a + b - 1) / b; }

__device__ __forceinline__ float leaky(float x){ return x > 0.f ? x : 0.2f * x; }

union H8 { float4 f4; __half2 h2[4]; };

typedef _Float16 f16x8 __attribute__((ext_vector_type(8)));
typedef float    f32x4 __attribute__((ext_vector_type(4)));

// ================= merged bucketed CSR build (round-16, proven) =================
__global__ void k_hist2(const int* __restrict__ dstM, const int* __restrict__ dstP,
                        int* __restrict__ coarseM, int* __restrict__ coarseP){
    __shared__ int lh[512];
    int t = threadIdx.x;
    const int* dst; int* coarse; int K, E, base, chunk;
    if (blockIdx.x < 256) { dst = dstM; coarse = coarseM; K = 512; E = EM; chunk = 2048; base = blockIdx.x * 2048; }
    else                  { dst = dstP; coarse = coarseP; K = 391; E = EP; chunk = 4096; base = (blockIdx.x - 256) * 4096; }
    for (int i = t; i < K; i += 256) lh[i] = 0;
    __syncthreads();
    int end = min(base + chunk, E);
    for (int e = base + t; e < end; e += 256)
        atomicAdd(&lh[dst[e] >> 8], 1);
    __syncthreads();
    for (int i = t; i < K; i += 256)
        if (lh[i]) atomicAdd(&coarse[i], lh[i]);
}

__global__ void k_scan2(const int* __restrict__ coarseM, int* __restrict__ cstartM, int* __restrict__ cursorM,
                        const int* __restrict__ coarseP, int* __restrict__ cstartP, int* __restrict__ cursorP){
    const int* coarse; int* cstart; int* cursor; int K;
    if (blockIdx.x == 0) { coarse = coarseM; cstart = cstartM; cursor = cursorM; K = 512; }
    else                 { coarse = coarseP; cstart = cstartP; cursor = cursorP; K = 391; }
    int t = threadIdx.x, lane = t & 63, wid = t >> 6;
    int v0 = (t < K) ? coarse[t] : 0;
    int v = v0;
    #pragma unroll
    for (int off = 1; off < 64; off <<= 1) {
        int x = __shfl_up(v, off, 64);
        if (lane >= off) v += x;
    }
    __shared__ int ws[8];
    if (lane == 63) ws[wid] = v;
    __syncthreads();
    int add = 0;
    for (int w = 0; w < wid; w++) add += ws[w];
    int excl = v + add - v0;
    if (t < K) { cstart[t] = excl; cursor[t] = excl; }
    if (t == K - 1) cstart[K] = excl + v0;
}

__global__ void k_part2(const int* __restrict__ eiM, int* __restrict__ cursorM, unsigned* __restrict__ bufM,
                        const int* __restrict__ eiP, int* __restrict__ cursorP, unsigned* __restrict__ bufP){
    __shared__ int lh[512];
    __shared__ int lbase[512];
    const int* ei; int* cursor; unsigned* buf; int E, K, base;
    if (blockIdx.x < 128) { ei = eiM; cursor = cursorM; buf = bufM; E = EM; K = 512; base = blockIdx.x * 4096; }
    else                  { ei = eiP; cursor = cursorP; buf = bufP; E = EP; K = 391; base = (blockIdx.x - 128) * 4096; }
    int t = threadIdx.x;
    for (int i = t; i < K; i += 256) lh[i] = 0;
    __syncthreads();
    int end = min(base + 4096, E);
    unsigned pay[16]; int bslot[16];
    int cnt = 0;
    for (int e = base + t; e < end; e += 256) {
        int u = ei[e], v = ei[E + e];
        int b = v >> 8;
        int ls = atomicAdd(&lh[b], 1);
        pay[cnt] = ((unsigned)(v & 255) << 24) | (unsigned)u;
        bslot[cnt] = (b << 13) | ls;
        cnt++;
    }
    __syncthreads();
    for (int i = t; i < K; i += 256)
        lbase[i] = lh[i] ? atomicAdd(&cursor[i], lh[i]) : 0;
    __syncthreads();
    for (int j = 0; j < cnt; j++) {
        int b = bslot[j] >> 13, ls = bslot[j] & 8191;
        buf[lbase[b] + ls] = pay[j];
    }
}

__global__ void k_fine2(const unsigned* __restrict__ bufM, const int* __restrict__ cstartM,
                        int* __restrict__ molRP, int* __restrict__ molCOL, float* __restrict__ dinv,
                        const unsigned* __restrict__ bufP, const int* __restrict__ cstartP,
                        int* __restrict__ protRP, int* __restrict__ protCOL){
    int t = threadIdx.x;
    int k; const unsigned* buf; const int* cstart; int* rp; int* col; int n, OB, dv;
    if (blockIdx.x < 512) { k = blockIdx.x;       buf = bufM; cstart = cstartM; rp = molRP;  col = molCOL;  n = NM; OB = 20; dv = 1; }
    else                  { k = blockIdx.x - 512; buf = bufP; cstart = cstartP; rp = protRP; col = protCOL; n = NP; OB = 21; dv = 0; }
    int start = cstart[k], end = cstart[k + 1];
    __shared__ int cnt[256];
    __shared__ int cur[256];
    cnt[t] = 0;
    __syncthreads();
    for (int p = start + t; p < end; p += 256)
        atomicAdd(&cnt[buf[p] >> 24], 1);
    __syncthreads();
    int v0 = cnt[t];
    int lane = t & 63, wid = t >> 6;
    int v = v0;
    #pragma unroll
    for (int off = 1; off < 64; off <<= 1) {
        int x = __shfl_up(v, off, 64);
        if (lane >= off) v += x;
    }
    __shared__ int ws[4];
    if (lane == 63) ws[wid] = v;
    __syncthreads();
    int add = 0;
    for (int w = 0; w < wid; w++) add += ws[w];
    int excl = v + add - v0;
    int ofs = start + excl;
    cur[t] = ofs;
    int idx = (k << 8) + t;
    if (idx < n) {
        rp[idx] = (int)((unsigned)ofs | ((unsigned)v0 << OB));
        if (dv) dinv[idx] = rsqrtf((float)(v0 + 1));
    }
    __syncthreads();
    for (int p = start + t; p < end; p += 256) {
        unsigned pk = buf[p];
        int slot = atomicAdd(&cur[pk >> 24], 1);
        col[slot] = (int)(pk & 0xFFFFFFu);
    }
}

// ================= merged prep: molprep (512) + segbounds (512) + prot prep (391) =================
__global__ void k_prep2(const float* __restrict__ mol_x, const float* __restrict__ dinv,
                        __half* __restrict__ x8, const int* __restrict__ batch,
                        int* __restrict__ gstart, int* __restrict__ gend,
                        const float* __restrict__ prot_x, const float* __restrict__ W1,
                        const float* __restrict__ as_, const float* __restrict__ ad_,
                        __half* __restrict__ x32, float* __restrict__ es,
                        float* __restrict__ ed_){
    __shared__ float vas[20], vds[20];
    int b = blockIdx.x, t = threadIdx.x;
    if (b < 512) {
        int i = b * 256 + t;
        float dd = dinv[i];
        H8 r;
        #pragma unroll
        for (int k = 0; k < 3; k++)
            r.h2[k] = __floats2half2_rn(dd * mol_x[i*6 + 2*k], dd * mol_x[i*6 + 2*k + 1]);
        r.h2[3] = __floats2half2_rn(0.f, 0.f);
        *(float4*)&x8[(size_t)i * 8] = r.f4;
    } else if (b < 1024) {
        int i = (b - 512) * 256 + t;
        int g = batch[i];
        if (i == 0 || batch[i - 1] != g) gstart[g] = i;
        if (i == NM - 1 || batch[i + 1] != g) gend[g] = i + 1;
    } else {
        if (t < 20) {
            float s = 0.f;
            for (int j = 0; j < 64; j++) s += W1[t * 64 + j] * as_[j];
            vas[t] = s;
        } else if (t >= 32 && t < 52) {
            int k = t - 32;
            float s = 0.f;
            for (int j = 0; j < 64; j++) s += W1[k * 64 + j] * ad_[j];
            vds[k] = s;
        }
        __syncthreads();
        int i = (b - 1024) * 256 + t;
        if (i >= NP) return;
        float xv[20];
        float s = 0.f, d = 0.f;
        #pragma unroll
        for (int k = 0; k < 20; k++) {
            xv[k] = prot_x[i*20 + k];
            s += xv[k] * vas[k]; d += xv[k] * vds[k];
        }
        es[i] = s; ed_[i] = d;
        H8 r0, r1, r2, rz;
        #pragma unroll
        for (int k = 0; k < 4; k++) r0.h2[k] = __floats2half2_rn(xv[2*k],   xv[2*k+1]);
        #pragma unroll
        for (int k = 0; k < 4; k++) r1.h2[k] = __floats2half2_rn(xv[8+2*k], xv[9+2*k]);
        r2.h2[0] = __floats2half2_rn(xv[16], xv[17]);
        r2.h2[1] = __floats2half2_rn(xv[18], xv[19]);
        r2.h2[2] = __floats2half2_rn(0.f, 0.f);
        r2.h2[3] = __floats2half2_rn(0.f, 0.f);
        rz.h2[0] = rz.h2[1] = rz.h2[2] = rz.h2[3] = __floats2half2_rn(0.f, 0.f);
        *(float4*)&x32[(size_t)i * 32]      = r0.f4;
        *(float4*)&x32[(size_t)i * 32 + 8]  = r1.f4;
        *(float4*)&x32[(size_t)i * 32 + 16] = r2.f4;
        *(float4*)&x32[(size_t)i * 32 + 24] = rz.f4;
    }
}

// ================= merged L1 gathers: mol (4096 blocks) + prot (25000 blocks) =================
__global__ void k_l1g2(const int* __restrict__ molRP, const int* __restrict__ molCOL,
                       const __half* __restrict__ x8, const float* __restrict__ dinv,
                       float* __restrict__ aggM,
                       const int* __restrict__ protRP, const int* __restrict__ protCOL,
                       const __half* __restrict__ x32, const float* __restrict__ es,
                       const float* __restrict__ ed_, float* __restrict__ aggP){
    __shared__ float ost[192];
    int tid = threadIdx.x;
    if (blockIdx.x < NM/32) {
        int bid = blockIdx.x;
        int wv = tid >> 6, l = tid & 63, g = l >> 3, q = l & 7;
        int node = (bid << 5) + (wv << 3) + g;
        unsigned pk = (unsigned)molRP[node];
        int s0 = (int)(pk & 0xFFFFFu);
        int deg = (int)(pk >> 20);
        float acc[6] = {0.f,0.f,0.f,0.f,0.f,0.f};
        if (q == 0) {
            H8 r; r.f4 = *(const float4*)&x8[(size_t)node * 8];
            #pragma unroll
            for (int i = 0; i < 3; i++) {
                float2 f = __half22float2(r.h2[i]);
                acc[2*i] = f.x; acc[2*i+1] = f.y;
            }
        }
        for (int base = 0; base < deg; base += 8) {
            int s = base + q;
            int c = molCOL[s0 + s];
            int u = (s < deg) ? c : node;
            float wvv = (s < deg) ? 1.f : 0.f;
            H8 r; r.f4 = *(const float4*)&x8[(size_t)u * 8];
            #pragma unroll
            for (int i = 0; i < 3; i++) {
                float2 f = __half22float2(r.h2[i]);
                acc[2*i] += wvv * f.x; acc[2*i+1] += wvv * f.y;
            }
        }
        #pragma unroll
        for (int m = 1; m < 8; m <<= 1) {
            #pragma unroll
            for (int i = 0; i < 6; i++) acc[i] += __shfl_xor(acc[i], m, 8);
        }
        if (q == 0) {
            float dd = dinv[node];
            int slot = (wv << 3) + g;
            #pragma unroll
            for (int i = 0; i < 6; i++) ost[slot * 6 + i] = dd * acc[i];
        }
        __syncthreads();
        if (tid < 48)
            *(float4*)&aggM[(size_t)bid * 192 + (tid << 2)] = *(float4*)&ost[tid << 2];
    } else {
        int bid = blockIdx.x - NM/32;
        int node = (bid << 2) + (tid >> 6);
        int l = tid & 63, g = l >> 2, q = l & 3;
        unsigned pk = (unsigned)protRP[node];
        int s0 = (int)(pk & 0x1FFFFFu);
        int deg = (int)(pk >> 21);
        float edv = ed_[node];
        float selfw = __expf(leaky(es[node] + edv));
        float acc[8] = {0.f,0.f,0.f,0.f,0.f,0.f,0.f,0.f};
        float den = (l == 0) ? selfw : 0.f;
        if (g == 0 && q < 3) {
            H8 r; r.f4 = *(const float4*)&x32[(size_t)node * 32 + (q << 3)];
            #pragma unroll
            for (int i = 0; i < 4; i++) {
                float2 f = __half22float2(r.h2[i]);
                acc[2*i] = selfw * f.x; acc[2*i+1] = selfw * f.y;
            }
        }
        for (int base = 0; base < deg; base += 16) {
            int s = base + g;
            int c = protCOL[s0 + s];
            int u = (s < deg) ? c : node;
            float wvv = (s < deg) ? __expf(leaky(es[u] + edv)) : 0.f;
            if (q < 3) {
                H8 r; r.f4 = *(const float4*)&x32[(size_t)u * 32 + (q << 3)];
                #pragma unroll
                for (int i = 0; i < 4; i++) {
                    float2 f = __half22float2(r.h2[i]);
                    acc[2*i] += wvv * f.x; acc[2*i+1] += wvv * f.y;
                }
            }
            if (q == 0) den += wvv;
        }
        #pragma unroll
        for (int m = 4; m <= 32; m <<= 1) {
            #pragma unroll
            for (int i = 0; i < 8; i++) acc[i] += __shfl_xor(acc[i], m, 64);
            den += __shfl_xor(den, m, 64);
        }
        den = __shfl(den, 0, 64);
        float inv = 1.f / den;
        if (g == 0) {
            if (q < 2) {
                float4 v0 = make_float4(acc[0]*inv, acc[1]*inv, acc[2]*inv, acc[3]*inv);
                float4 v1 = make_float4(acc[4]*inv, acc[5]*inv, acc[6]*inv, acc[7]*inv);
                *(float4*)&aggP[(size_t)node * 20 + (q << 3)]     = v0;
                *(float4*)&aggP[(size_t)node * 20 + (q << 3) + 4] = v1;
            } else if (q == 2) {
                float4 v0 = make_float4(acc[0]*inv, acc[1]*inv, acc[2]*inv, acc[3]*inv);
                *(float4*)&aggP[(size_t)node * 20 + 16] = v0;
            }
        }
    }
}

// ================= merged MLP via MFMA (f16 16x16x32), 64 nodes/block, 4 waves =================
// LDS (halves): W1T [64][40] @0, W2T [64][72] @2560, Ain [4][16][40] @7168, X1 [4][16][72] @9728
// Fragment layouts (HW-verified, learn_hip m89/m91):
//   A: row=lane&15, k=8*(lane>>4)+j (contiguous 16B)  B: col=lane&15, same k
//   D: col=lane&15, row=4*(lane>>4)+r
template<int D, int ATT, int SCALE>
__device__ __forceinline__ void mlp_mfma(__half* smemh, int bid, int tid,
                                         const float* __restrict__ agg, const float* __restrict__ W1,
                                         const float* __restrict__ b1, const float* __restrict__ W2,
                                         const float* __restrict__ as_, const float* __restrict__ ad_,
                                         __half* __restrict__ hout, float* __restrict__ es,
                                         float* __restrict__ ed_, const float* __restrict__ dinv,
                                         int n){
    __half* W1Ts = smemh;            // 64*40 = 2560 halves (k in [32,40) never read)
    __half* W2Ts = smemh + 2560;     // 64*72 = 4608 halves (k in [64,72) never read)
    __half* AinS = smemh + 7168;     // 4 waves * 16 rows * 40 k
    __half* X1S  = smemh + 9728;     // 4 waves * 16 rows * 72 cols
    int lane = tid & 63, w = tid >> 6;
    int c = lane & 15, g = lane >> 4;
    int node0 = bid * 64 + w * 16;

    // ---- stage transposed f16 weights (whole block, coalesced reads) ----
    for (int idx = tid; idx < 2048; idx += 256) {
        int k = idx >> 6, col = idx & 63;
        W1Ts[col * 40 + k] = __float2half(k < D ? W1[k * 64 + col] : 0.f);
    }
    for (int idx = tid; idx < 4096; idx += 256) {
        int k = idx >> 6, col = idx & 63;
        W2Ts[col * 72 + k] = __float2half(W2[k * 64 + col]);
    }
    // ---- zero + stage A rows (per wave, coalesced: rows are consecutive nodes) ----
    {
        float4 z4 = make_float4(0.f, 0.f, 0.f, 0.f);
        float4* az = (float4*)(AinS + w * 640);
        for (int i = lane; i < 80; i += 64) az[i] = z4;
        int lim = 16 * D;
        if (ATT) { int rem = n - node0; if (rem < 0) rem = 0; if (rem < 16) lim = rem * D; }
        const float* aw = agg + (size_t)node0 * D;
        for (int idx = lane; idx < lim; idx += 64) {
            int r = idx / D, k = idx - r * D;
            AinS[w * 640 + r * 40 + k] = __float2half(aw[idx]);
        }
    }
    __syncthreads();

    // ---- layer 1: [16 x K<=32] @ [K x 64] -> bias + relu -> X1 in LDS ----
    f32x4 zz = {0.f, 0.f, 0.f, 0.f};
    f16x8 a1 = *(const f16x8*)&AinS[w * 640 + c * 40 + 8 * g];
    #pragma unroll
    for (int t = 0; t < 4; t++) {
        f16x8 b = *(const f16x8*)&W1Ts[(16 * t + c) * 40 + 8 * g];
        f32x4 h = __builtin_amdgcn_mfma_f32_16x16x32_f16(a1, b, zz, 0, 0, 0);
        float bv = b1[16 * t + c];
        #pragma unroll
        for (int r = 0; r < 4; r++) {
            float v = fmaxf(h[r] + bv, 0.f);
            X1S[w * 1152 + (4 * g + r) * 72 + 16 * t + c] = __float2half(v);
        }
    }
    __syncthreads();

    // ---- layer 2: [16 x 64] @ [64 x 64] ----
    f32x4 acc[4];
    #pragma unroll
    for (int t = 0; t < 4; t++) acc[t] = zz;
    #pragma unroll
    for (int kt = 0; kt < 2; kt++) {
        f16x8 a = *(const f16x8*)&X1S[w * 1152 + c * 72 + 32 * kt + 8 * g];
        #pragma unroll
        for (int t = 0; t < 4; t++) {
            f16x8 b = *(const f16x8*)&W2Ts[(16 * t + c) * 72 + 32 * kt + 8 * g];
            acc[t] = __builtin_amdgcn_mfma_f32_16x16x32_f16(a, b, acc[t], 0, 0, 0);
        }
    }

    // ---- attention dots (prot): reduce row over 16 col-lanes ----
    if (ATT) {
        float asv[4], adv[4];
        #pragma unroll
        for (int t = 0; t < 4; t++) { asv[t] = as_[16 * t + c]; adv[t] = ad_[16 * t + c]; }
        #pragma unroll
        for (int r = 0; r < 4; r++) {
            float xa = 0.f, ya = 0.f;
            #pragma unroll
            for (int t = 0; t < 4; t++) { xa += acc[t][r] * asv[t]; ya += acc[t][r] * adv[t]; }
            #pragma unroll
            for (int m = 1; m < 16; m <<= 1) { xa += __shfl_xor(xa, m, 16); ya += __shfl_xor(ya, m, 16); }
            int nd = node0 + 4 * g + r;
            if (c == 0 && nd < n) { es[nd] = xa; ed_[nd] = ya; }
        }
    }
    // ---- pre-scale by dinv (mol) ----
    if (SCALE) {
        #pragma unroll
        for (int r = 0; r < 4; r++) {
            float dd = dinv[node0 + 4 * g + r];
            #pragma unroll
            for (int t = 0; t < 4; t++) acc[t][r] *= dd;
        }
    }

    // ---- repack through LDS (reuse X1 slab) -> coalesced float4 f16 stores ----
    #pragma unroll
    for (int t = 0; t < 4; t++) {
        #pragma unroll
        for (int r = 0; r < 4; r++)
            X1S[w * 1152 + (4 * g + r) * 72 + 16 * t + c] = __float2half(acc[t][r]);
    }
    __syncthreads();
    int rr = lane >> 2, seg = lane & 3;
    union { f16x8 h; float4 f; } o;
    o.h = *(const f16x8*)&X1S[w * 1152 + rr * 72 + seg * 16];
    int nd = node0 + rr;
    if (!ATT || nd < n)
        *(float4*)&hout[(size_t)nd * 64 + seg * 16] = o.f;
}

__global__ void k_mlp2(const float* __restrict__ aggM, const float* __restrict__ gcn_w1,
                       const float* __restrict__ gcn_b1, const float* __restrict__ gcn_w2,
                       __half* __restrict__ h2hM, const float* __restrict__ dinvM,
                       const float* __restrict__ aggP, const float* __restrict__ gat_w1,
                       const float* __restrict__ gat_b1, const float* __restrict__ gat_w2,
                       const float* __restrict__ as2, const float* __restrict__ ad2,
                       __half* __restrict__ h2hP, float* __restrict__ es, float* __restrict__ ed_){
    __shared__ __attribute__((aligned(16))) __half smemh[14336];   // 28672 B -> 5 blocks/CU
    if (blockIdx.x < NM/64)
        mlp_mfma<6, 0, 1>(smemh, blockIdx.x, threadIdx.x, aggM, gcn_w1, gcn_b1, gcn_w2,
                          nullptr, nullptr, h2hM, nullptr, nullptr, dinvM, NM);
    else
        mlp_mfma<20, 1, 0>(smemh, blockIdx.x - NM/64, threadIdx.x, aggP, gat_w1, gat_b1, gat_w2,
                           as2, ad2, h2hP, es, ed_, nullptr, NP);
}

// ---------------- prot layer-2 gather: 8 groups x 8 lanes, 2 slots/group, fp16 out ----------------
__global__ void k_gather64h_gat(const int* __restrict__ rp, const int* __restrict__ col,
                                const __half* __restrict__ hh, const float* __restrict__ es,
                                const float* __restrict__ ed_, const float* __restrict__ b,
                                __half* __restrict__ out_h){
    int tid = threadIdx.x;
    int node = (blockIdx.x << 2) + (tid >> 6);
    int l = tid & 63, g = l >> 3, q = l & 7;
    unsigned pk = (unsigned)rp[node];
    int s0 = (int)(pk & 0x1FFFFFu);
    int deg = (int)(pk >> 21);
    float edv = ed_[node];
    float selfw = __expf(leaky(es[node] + edv));
    float acc[8] = {0.f,0.f,0.f,0.f,0.f,0.f,0.f,0.f};
    float den = (l == 0) ? selfw : 0.f;
    if (g == 0) {
        H8 r; r.f4 = *(const float4*)&hh[(size_t)node * 64 + (q << 3)];
        #pragma unroll
        for (int i = 0; i < 4; i++) {
            float2 f = __half22float2(r.h2[i]);
            acc[2*i]     = selfw * f.x;
            acc[2*i + 1] = selfw * f.y;
        }
    }
    for (int base = 0; base < deg; base += 16) {
        int sA = base + g, sB = base + g + 8;
        int cA = col[s0 + sA], cB = col[s0 + sB];
        int uA = (sA < deg) ? cA : node;
        int uB = (sB < deg) ? cB : node;
        float eA = es[uA], eB = es[uB];
        float wA = (sA < deg) ? __expf(leaky(eA + edv)) : 0.f;
        float wB = (sB < deg) ? __expf(leaky(eB + edv)) : 0.f;
        H8 rA, rB;
        rA.f4 = *(const float4*)&hh[(size_t)uA * 64 + (q << 3)];
        rB.f4 = *(const float4*)&hh[(size_t)uB * 64 + (q << 3)];
        #pragma unroll
        for (int i = 0; i < 4; i++) {
            float2 fA = __half22float2(rA.h2[i]);
            float2 fB = __half22float2(rB.h2[i]);
            acc[2*i]     += wA * fA.x + wB * fB.x;
            acc[2*i + 1] += wA * fA.y + wB * fB.y;
        }
        if (q == 0) den += wA + wB;
    }
    #pragma unroll
    for (int m = 8; m <= 32; m <<= 1) {
        #pragma unroll
        for (int i = 0; i < 8; i++) acc[i] += __shfl_xor(acc[i], m, 64);
        den += __shfl_xor(den, m, 64);
    }
    den = __shfl(den, 0, 64);
    if (g == 0) {
        float sc = 1.f / den;
        int f = q << 3;
        H8 o;
        #pragma unroll
        for (int i = 0; i < 4; i++)
            o.h2[i] = __floats2half2_rn(acc[2*i]*sc + b[f + 2*i], acc[2*i+1]*sc + b[f + 2*i + 1]);
        *(float4*)&out_h[(size_t)node * 64 + f] = o.f4;
    }
}

// ---------------- mol layer-2 gather: 8 slots x 8 lanes, pre-scaled rows, fp16 out ----------------
__global__ void k_gather64h_gcn(const int* __restrict__ rp, const int* __restrict__ col,
                                const __half* __restrict__ hh, const float* __restrict__ dinv,
                                const float* __restrict__ b, __half* __restrict__ out_h){
    int tid = threadIdx.x;
    int node = (blockIdx.x << 2) + (tid >> 6);
    int l = tid & 63, g = l >> 3, q = l & 7;
    unsigned pk = (unsigned)rp[node];
    int s0 = (int)(pk & 0xFFFFFu);
    int deg = (int)(pk >> 20);
    float acc[8] = {0.f,0.f,0.f,0.f,0.f,0.f,0.f,0.f};
    if (g == 0) {
        H8 r; r.f4 = *(const float4*)&hh[(size_t)node * 64 + (q << 3)];
        #pragma unroll
        for (int i = 0; i < 4; i++) {
            float2 f = __half22float2(r.h2[i]);
            acc[2*i]     = f.x;
            acc[2*i + 1] = f.y;
        }
    }
    for (int base = 0; base < deg; base += 8) {
        int s = base + g;
        int c = col[s0 + s];
        int u = (s < deg) ? c : node;
        float wvv = (s < deg) ? 1.f : 0.f;
        H8 r; r.f4 = *(const float4*)&hh[(size_t)u * 64 + (q << 3)];
        #pragma unroll
        for (int i = 0; i < 4; i++) {
            float2 f = __half22float2(r.h2[i]);
            acc[2*i]     += wvv * f.x;
            acc[2*i + 1] += wvv * f.y;
        }
    }
    #pragma unroll
    for (int m = 8; m <= 32; m <<= 1) {
        #pragma unroll
        for (int i = 0; i < 8; i++) acc[i] += __shfl_xor(acc[i], m, 64);
    }
    if (g == 0) {
        float sc = dinv[node];
        int f = q << 3;
        H8 o;
        #pragma unroll
        for (int i = 0; i < 4; i++)
            o.h2[i] = __floats2half2_rn(acc[2*i]*sc + b[f + 2*i], acc[2*i+1]*sc + b[f + 2*i + 1]);
        *(float4*)&out_h[(size_t)node * 64 + f] = o.f4;
    }
}

// ================= merged pools: segpool fp16 (1024 blocks) + prot pool fp16 (1024) =================
__global__ void k_pool2(const int* __restrict__ gstart, const int* __restrict__ gend,
                        const __half* __restrict__ molout_h, float* __restrict__ gsum,
                        const __half* __restrict__ protout_h, float* __restrict__ psum){
    __shared__ float red[4][64];
    int t = threadIdx.x;
    if (blockIdx.x < 1024) {
        // 4 graphs per block, one wave each
        int wv = t >> 6, l = t & 63, rg = l >> 4, q = l & 15;
        int gph = (blockIdx.x << 2) + wv;
        int s = gstart[gph], c = gend[gph] - gstart[gph];
        float4 a = {0.f, 0.f, 0.f, 0.f};
        for (int i = rg; i < c; i += 4) {
            __half2 h0 = *(const __half2*)&molout_h[(size_t)(s + i) * 64 + (q << 2)];
            __half2 h1 = *(const __half2*)&molout_h[(size_t)(s + i) * 64 + (q << 2) + 2];
            float2 f0 = __half22float2(h0), f1 = __half22float2(h1);
            a.x += f0.x; a.y += f0.y; a.z += f1.x; a.w += f1.y;
        }
        #pragma unroll
        for (int m = 16; m <= 32; m <<= 1) {
            a.x += __shfl_xor(a.x, m, 64);
            a.y += __shfl_xor(a.y, m, 64);
            a.z += __shfl_xor(a.z, m, 64);
            a.w += __shfl_xor(a.w, m, 64);
        }
        if (rg == 0) *(float4*)&gsum[gph * 64 + (q << 2)] = a;
    } else {
        // grid-stride over NP*8 chunks of 8 halves; phase = chunk & 7
        const float4* p4 = (const float4*)protout_h;
        const int TC = NP * 8;
        float acc[8] = {0.f,0.f,0.f,0.f,0.f,0.f,0.f,0.f};
        for (int i = (blockIdx.x - 1024) * 256 + t; i < TC; i += 1024 * 256) {
            H8 r; r.f4 = p4[i];
            #pragma unroll
            for (int j = 0; j < 4; j++) {
                float2 f = __half22float2(r.h2[j]);
                acc[2*j] += f.x; acc[2*j+1] += f.y;
            }
        }
        int lane = t & 63, wv = t >> 6;
        #pragma unroll
        for (int m = 8; m <= 32; m <<= 1) {
            #pragma unroll
            for (int j = 0; j < 8; j++) acc[j] += __shfl_xor(acc[j], m, 64);
        }
        if (lane < 8) {
            #pragma unroll
            for (int j = 0; j < 8; j++) red[wv][lane * 8 + j] = acc[j];
        }
        __syncthreads();
        if (t < 64) {
            float s = red[0][t] + red[1][t] + red[2][t] + red[3][t];
            atomicAdd(&psum[t], s);
        }
    }
}

// ---------------- fused classifier ----------------
__global__ void k_cls(const float* __restrict__ gsum, const int* __restrict__ gstart,
                      const int* __restrict__ gend, const float* __restrict__ psum,
                      const float* __restrict__ W1, const float* __restrict__ b1,
                      const float* __restrict__ w2, const float* __restrict__ b2,
                      float* __restrict__ out){
    __shared__ float W1s[128 * 64];
    int tid = threadIdx.x;
    for (int k = tid; k < 128 * 64; k += 256) W1s[k] = W1[k];
    __syncthreads();
    int g = blockIdx.x * 4 + (tid >> 6);
    int j = tid & 63;
    float cntf = (float)(gend[g] - gstart[g]);
    float inv = 1.0f / fmaxf(cntf, 1.0f);
    const float invp = 1.0f / (float)NP;
    float acc = b1[j];
    #pragma unroll 8
    for (int k = 0; k < 64; k++) acc += (gsum[g * 64 + k] * inv) * W1s[k * 64 + j];
    #pragma unroll 8
    for (int k = 0; k < 64; k++) acc += (psum[k] * invp) * W1s[(64 + k) * 64 + j];
    float v = fmaxf(acc, 0.f) * w2[j];
    #pragma unroll
    for (int off = 32; off > 0; off >>= 1) v += __shfl_down(v, off, 64);
    if (j == 0) out[g] = 1.0f / (1.0f + expf(-(v + b2[0])));
}

extern "C" void kernel_launch(void* const* d_in, const int* in_sizes, int n_in,
                              void* d_out, int out_size, void* d_ws, size_t ws_size,
                              hipStream_t stream) {
    const float* mol_x   = (const float*)d_in[0];
    const int*   mol_ei  = (const int*)d_in[1];
    const int*   mol_bat = (const int*)d_in[2];
    const float* prot_x  = (const float*)d_in[3];
    const int*   prot_ei = (const int*)d_in[4];
    const float* gcn_w1  = (const float*)d_in[5];
    const float* gcn_b1  = (const float*)d_in[6];
    const float* gcn_w2  = (const float*)d_in[7];
    const float* gcn_b2  = (const float*)d_in[8];
    const float* gat_w1  = (const float*)d_in[9];
    const float* gat_as1 = (const float*)d_in[10];
    const float* gat_ad1 = (const float*)d_in[11];
    const float* gat_b1  = (const float*)d_in[12];
    const float* gat_w2  = (const float*)d_in[13];
    const float* gat_as2 = (const float*)d_in[14];
    const float* gat_ad2 = (const float*)d_in[15];
    const float* gat_b2  = (const float*)d_in[16];
    const float* cls_w1  = (const float*)d_in[17];
    const float* cls_b1  = (const float*)d_in[18];
    const float* cls_w2  = (const float*)d_in[19];
    const float* cls_b2  = (const float*)d_in[20];
    float* out = (float*)d_out;

    float* ws_f = (float*)d_ws;

    // ---- persistent tail; [gstart .. coarseP+512) is one contiguous zeroed region ----
    float* T       = ws_f + 16777216;
    float* gsum    = T;                       // 262,144 floats (no init needed)
    int*   gstart  = (int*)(T + 262144);      // 4,096 ints (zeroed)
    int*   gend    = (int*)(T + 266240);      // 4,096 ints (zeroed)
    float* psum    = T + 270336;              // 64 floats (zeroed)
    int*   coarseM = (int*)(T + 270400);      // 512 ints (zeroed)
    int*   coarseP = (int*)(T + 270912);      // 512 ints (zeroed)
    int*   cstartM = (int*)(T + 271424);      // 513
    int*   cursorM = (int*)(T + 271937);      // 512
    int*   cstartP = (int*)(T + 272449);      // 513
    int*   cursorP = (int*)(T + 272962);      // 512

    // ---- early CSR staging (dead after k_fine2) ----
    unsigned* bufM = (unsigned*)ws_f;                    // [0, 524,288)
    unsigned* bufP = (unsigned*)(ws_f + 524352);         // [524,352, 2,124,416)

    // ---- overlapping phase regions (all offsets in floats) ----
    __half*   h2hP      = (__half*)ws_f;
    __half*   molout_h  = (__half*)ws_f;
    __half*   x32h      = (__half*)(ws_f + 4194304);
    __half*   protout_h = (__half*)(ws_f + 4194304);
    float*    aggP      = ws_f + 5794304;
    float*    es        = ws_f + 7794304;
    float*    ed_       = ws_f + 7894304;
    __half*   h2hM      = (__half*)(ws_f + 8388608);
    int*      molCOL    = (int*)(ws_f + 12582912);       // EM+64 -> 13,107,264
    int*      molRP     = (int*)(ws_f + 13107264);       // NM -> 13,238,336 (+pad)
    float*    dinvM     = ws_f + 13238352;               // NM -> 13,369,424 (+pad)
    __half*   x8h       = (__half*)(ws_f + 13369440);    // NM*8 halves -> 13,893,728 (+pad)
    float*    aggM      = ws_f + 13893792;               // NM*6 -> 14,680,224 (+pad)
    int*      protCOL   = (int*)(ws_f + 14680256);       // EP+64 -> 16,280,320
    int*      protRP    = (int*)(ws_f + 16280320);       // NP -> 16,380,320

    // single upfront zero of gstart+gend+psum+coarseM+coarseP (contiguous)
    (void)hipMemsetAsync(gstart, 0, (size_t)(4096 + 4096 + 64 + 512 + 512) * sizeof(int), stream);

    // ================= merged CSR build (mol + prot) =================
    k_hist2<<<256 + 391, 256, 0, stream>>>(mol_ei + EM, prot_ei + EP, coarseM, coarseP);
    k_scan2<<<2, 512, 0, stream>>>(coarseM, cstartM, cursorM, coarseP, cstartP, cursorP);
    k_part2<<<128 + 391, 256, 0, stream>>>(mol_ei, cursorM, bufM, prot_ei, cursorP, bufP);
    k_fine2<<<512 + 391, 256, 0, stream>>>(bufM, cstartM, molRP, molCOL, dinvM,
                                           bufP, cstartP, protRP, protCOL);

    // ================= merged preps =================
    k_prep2<<<512 + 512 + 391, 256, 0, stream>>>(mol_x, dinvM, x8h, mol_bat, gstart, gend,
                                                 prot_x, gat_w1, gat_as1, gat_ad1, x32h, es, ed_);

    // ================= merged L1 gathers =================
    k_l1g2<<<NM/32 + NP/4, 256, 0, stream>>>(molRP, molCOL, x8h, dinvM, aggM,
                                             protRP, protCOL, x32h, es, ed_, aggP);

    // ================= merged MLPs (MFMA, 64 nodes/block) =================
    k_mlp2<<<NM/64 + cdiv(NP, 64), 256, 0, stream>>>(aggM, gcn_w1, gcn_b1, gcn_w2, h2hM, dinvM,
                                                     aggP, gat_w1, gat_b1, gat_w2, gat_as2, gat_ad2,
                                                     h2hP, es, ed_);

    // ================= L2 gathers (gat first: gcn's molout_h overwrites h2hP) =================
    k_gather64h_gat<<<NP/4, 256, 0, stream>>>(protRP, protCOL, h2hP, es, ed_, gat_b2, protout_h);
    k_gather64h_gcn<<<NM/4, 256, 0, stream>>>(molRP, molCOL, h2hM, dinvM, gcn_b2, molout_h);

    // ================= merged pools =================
    k_pool2<<<1024 + 1024, 256, 0, stream>>>(gstart, gend, molout_h, gsum, protout_h, psum);

    // ================= classifier =================
    k_cls<<<NG/4, 256, 0, stream>>>(gsum, gstart, gend, psum, cls_w1, cls_b1, cls_w2, cls_b2, out);
}

// Round 2
// 357.855 us; speedup vs baseline: 1.1351x; 1.0385x over previous
//
#include <hip/hip_runtime.h>
#include <hip/hip_fp16.h>

#define NM 131072   // mol nodes
#define EM 524288   // mol edges
#define NG 4096     // graphs
#define DM 6        // mol in dim
#define NP 100000   // prot nodes
#define EP 1600000  // prot edges
#define DP 20       // prot in dim

static inline int cdiv(int a, int b){ return (a + b - 1) / b; }

__device__ __forceinline__ float leaky(float x){ return x > 0.f ? x : 0.2f * x; }

union H8 { float4 f4; __half2 h2[4]; };

typedef _Float16 f16x8 __attribute__((ext_vector_type(8)));
typedef float    f32x4 __attribute__((ext_vector_type(4)));

// ================= merged bucketed CSR build (round-16, proven) =================
__global__ void k_hist2(const int* __restrict__ dstM, const int* __restrict__ dstP,
                        int* __restrict__ coarseM, int* __restrict__ coarseP){
    __shared__ int lh[512];
    int t = threadIdx.x;
    const int* dst; int* coarse; int K, E, base, chunk;
    if (blockIdx.x < 256) { dst = dstM; coarse = coarseM; K = 512; E = EM; chunk = 2048; base = blockIdx.x * 2048; }
    else                  { dst = dstP; coarse = coarseP; K = 391; E = EP; chunk = 4096; base = (blockIdx.x - 256) * 4096; }
    for (int i = t; i < K; i += 256) lh[i] = 0;
    __syncthreads();
    int end = min(base + chunk, E);
    for (int e = base + t; e < end; e += 256)
        atomicAdd(&lh[dst[e] >> 8], 1);
    __syncthreads();
    for (int i = t; i < K; i += 256)
        if (lh[i]) atomicAdd(&coarse[i], lh[i]);
}

__global__ void k_scan2(const int* __restrict__ coarseM, int* __restrict__ cstartM, int* __restrict__ cursorM,
                        const int* __restrict__ coarseP, int* __restrict__ cstartP, int* __restrict__ cursorP){
    const int* coarse; int* cstart; int* cursor; int K;
    if (blockIdx.x == 0) { coarse = coarseM; cstart = cstartM; cursor = cursorM; K = 512; }
    else                 { coarse = coarseP; cstart = cstartP; cursor = cursorP; K = 391; }
    int t = threadIdx.x, lane = t & 63, wid = t >> 6;
    int v0 = (t < K) ? coarse[t] : 0;
    int v = v0;
    #pragma unroll
    for (int off = 1; off < 64; off <<= 1) {
        int x = __shfl_up(v, off, 64);
        if (lane >= off) v += x;
    }
    __shared__ int ws[8];
    if (lane == 63) ws[wid] = v;
    __syncthreads();
    int add = 0;
    for (int w = 0; w < wid; w++) add += ws[w];
    int excl = v + add - v0;
    if (t < K) { cstart[t] = excl; cursor[t] = excl; }
    if (t == K - 1) cstart[K] = excl + v0;
}

__global__ void k_part2(const int* __restrict__ eiM, int* __restrict__ cursorM, unsigned* __restrict__ bufM,
                        const int* __restrict__ eiP, int* __restrict__ cursorP, unsigned* __restrict__ bufP){
    __shared__ int lh[512];
    __shared__ int lbase[512];
    const int* ei; int* cursor; unsigned* buf; int E, K, base;
    if (blockIdx.x < 128) { ei = eiM; cursor = cursorM; buf = bufM; E = EM; K = 512; base = blockIdx.x * 4096; }
    else                  { ei = eiP; cursor = cursorP; buf = bufP; E = EP; K = 391; base = (blockIdx.x - 128) * 4096; }
    int t = threadIdx.x;
    for (int i = t; i < K; i += 256) lh[i] = 0;
    __syncthreads();
    int end = min(base + 4096, E);
    unsigned pay[16]; int bslot[16];
    int cnt = 0;
    for (int e = base + t; e < end; e += 256) {
        int u = ei[e], v = ei[E + e];
        int b = v >> 8;
        int ls = atomicAdd(&lh[b], 1);
        pay[cnt] = ((unsigned)(v & 255) << 24) | (unsigned)u;
        bslot[cnt] = (b << 13) | ls;
        cnt++;
    }
    __syncthreads();
    for (int i = t; i < K; i += 256)
        lbase[i] = lh[i] ? atomicAdd(&cursor[i], lh[i]) : 0;
    __syncthreads();
    for (int j = 0; j < cnt; j++) {
        int b = bslot[j] >> 13, ls = bslot[j] & 8191;
        buf[lbase[b] + ls] = pay[j];
    }
}

__global__ void k_fine2(const unsigned* __restrict__ bufM, const int* __restrict__ cstartM,
                        int* __restrict__ molRP, int* __restrict__ molCOL, float* __restrict__ dinv,
                        const unsigned* __restrict__ bufP, const int* __restrict__ cstartP,
                        int* __restrict__ protRP, int* __restrict__ protCOL){
    int t = threadIdx.x;
    int k; const unsigned* buf; const int* cstart; int* rp; int* col; int n, OB, dv;
    if (blockIdx.x < 512) { k = blockIdx.x;       buf = bufM; cstart = cstartM; rp = molRP;  col = molCOL;  n = NM; OB = 20; dv = 1; }
    else                  { k = blockIdx.x - 512; buf = bufP; cstart = cstartP; rp = protRP; col = protCOL; n = NP; OB = 21; dv = 0; }
    int start = cstart[k], end = cstart[k + 1];
    __shared__ int cnt[256];
    __shared__ int cur[256];
    cnt[t] = 0;
    __syncthreads();
    for (int p = start + t; p < end; p += 256)
        atomicAdd(&cnt[buf[p] >> 24], 1);
    __syncthreads();
    int v0 = cnt[t];
    int lane = t & 63, wid = t >> 6;
    int v = v0;
    #pragma unroll
    for (int off = 1; off < 64; off <<= 1) {
        int x = __shfl_up(v, off, 64);
        if (lane >= off) v += x;
    }
    __shared__ int ws[4];
    if (lane == 63) ws[wid] = v;
    __syncthreads();
    int add = 0;
    for (int w = 0; w < wid; w++) add += ws[w];
    int excl = v + add - v0;
    int ofs = start + excl;
    cur[t] = ofs;
    int idx = (k << 8) + t;
    if (idx < n) {
        rp[idx] = (int)((unsigned)ofs | ((unsigned)v0 << OB));
        if (dv) dinv[idx] = rsqrtf((float)(v0 + 1));
    }
    __syncthreads();
    for (int p = start + t; p < end; p += 256) {
        unsigned pk = buf[p];
        int slot = atomicAdd(&cur[pk >> 24], 1);
        col[slot] = (int)(pk & 0xFFFFFFu);
    }
}

// ================= merged prep: molprep (512) + segbounds (512) + prot prep (391) =================
__global__ void k_prep2(const float* __restrict__ mol_x, const float* __restrict__ dinv,
                        __half* __restrict__ x8, const int* __restrict__ batch,
                        int* __restrict__ gstart, int* __restrict__ gend,
                        const float* __restrict__ prot_x, const float* __restrict__ W1,
                        const float* __restrict__ as_, const float* __restrict__ ad_,
                        __half* __restrict__ x32, float* __restrict__ es,
                        float* __restrict__ ed_){
    __shared__ float vas[20], vds[20];
    int b = blockIdx.x, t = threadIdx.x;
    if (b < 512) {
        int i = b * 256 + t;
        float dd = dinv[i];
        H8 r;
        #pragma unroll
        for (int k = 0; k < 3; k++)
            r.h2[k] = __floats2half2_rn(dd * mol_x[i*6 + 2*k], dd * mol_x[i*6 + 2*k + 1]);
        r.h2[3] = __floats2half2_rn(0.f, 0.f);
        *(float4*)&x8[(size_t)i * 8] = r.f4;
    } else if (b < 1024) {
        int i = (b - 512) * 256 + t;
        int g = batch[i];
        if (i == 0 || batch[i - 1] != g) gstart[g] = i;
        if (i == NM - 1 || batch[i + 1] != g) gend[g] = i + 1;
    } else {
        if (t < 20) {
            float s = 0.f;
            for (int j = 0; j < 64; j++) s += W1[t * 64 + j] * as_[j];
            vas[t] = s;
        } else if (t >= 32 && t < 52) {
            int k = t - 32;
            float s = 0.f;
            for (int j = 0; j < 64; j++) s += W1[k * 64 + j] * ad_[j];
            vds[k] = s;
        }
        __syncthreads();
        int i = (b - 1024) * 256 + t;
        if (i >= NP) return;
        float xv[20];
        float s = 0.f, d = 0.f;
        #pragma unroll
        for (int k = 0; k < 20; k++) {
            xv[k] = prot_x[i*20 + k];
            s += xv[k] * vas[k]; d += xv[k] * vds[k];
        }
        es[i] = s; ed_[i] = d;
        H8 r0, r1, r2, rz;
        #pragma unroll
        for (int k = 0; k < 4; k++) r0.h2[k] = __floats2half2_rn(xv[2*k],   xv[2*k+1]);
        #pragma unroll
        for (int k = 0; k < 4; k++) r1.h2[k] = __floats2half2_rn(xv[8+2*k], xv[9+2*k]);
        r2.h2[0] = __floats2half2_rn(xv[16], xv[17]);
        r2.h2[1] = __floats2half2_rn(xv[18], xv[19]);
        r2.h2[2] = __floats2half2_rn(0.f, 0.f);
        r2.h2[3] = __floats2half2_rn(0.f, 0.f);
        rz.h2[0] = rz.h2[1] = rz.h2[2] = rz.h2[3] = __floats2half2_rn(0.f, 0.f);
        *(float4*)&x32[(size_t)i * 32]      = r0.f4;
        *(float4*)&x32[(size_t)i * 32 + 8]  = r1.f4;
        *(float4*)&x32[(size_t)i * 32 + 16] = r2.f4;
        *(float4*)&x32[(size_t)i * 32 + 24] = rz.f4;
    }
}

// ================= merged L1 gathers: mol (4096 blocks) + prot (6250 blocks, 4 nodes/wave) =================
__global__ void k_l1g2(const int* __restrict__ molRP, const int* __restrict__ molCOL,
                       const __half* __restrict__ x8, const float* __restrict__ dinv,
                       float* __restrict__ aggM,
                       const int* __restrict__ protRP, const int* __restrict__ protCOL,
                       const __half* __restrict__ x32, const float* __restrict__ es,
                       const float* __restrict__ ed_, float* __restrict__ aggP){
    __shared__ float ost[192];
    int tid = threadIdx.x;
    if (blockIdx.x < NM/32) {
        int bid = blockIdx.x;
        int wv = tid >> 6, l = tid & 63, g = l >> 3, q = l & 7;
        int node = (bid << 5) + (wv << 3) + g;
        unsigned pk = (unsigned)molRP[node];
        int s0 = (int)(pk & 0xFFFFFu);
        int deg = (int)(pk >> 20);
        float acc[6] = {0.f,0.f,0.f,0.f,0.f,0.f};
        if (q == 0) {
            H8 r; r.f4 = *(const float4*)&x8[(size_t)node * 8];
            #pragma unroll
            for (int i = 0; i < 3; i++) {
                float2 f = __half22float2(r.h2[i]);
                acc[2*i] = f.x; acc[2*i+1] = f.y;
            }
        }
        for (int base = 0; base < deg; base += 8) {
            int s = base + q;
            int c = molCOL[s0 + s];
            int u = (s < deg) ? c : node;
            float wvv = (s < deg) ? 1.f : 0.f;
            H8 r; r.f4 = *(const float4*)&x8[(size_t)u * 8];
            #pragma unroll
            for (int i = 0; i < 3; i++) {
                float2 f = __half22float2(r.h2[i]);
                acc[2*i] += wvv * f.x; acc[2*i+1] += wvv * f.y;
            }
        }
        #pragma unroll
        for (int m = 1; m < 8; m <<= 1) {
            #pragma unroll
            for (int i = 0; i < 6; i++) acc[i] += __shfl_xor(acc[i], m, 8);
        }
        if (q == 0) {
            float dd = dinv[node];
            int slot = (wv << 3) + g;
            #pragma unroll
            for (int i = 0; i < 6; i++) ost[slot * 6 + i] = dd * acc[i];
        }
        __syncthreads();
        if (tid < 48)
            *(float4*)&aggM[(size_t)bid * 192 + (tid << 2)] = *(float4*)&ost[tid << 2];
    } else {
        // prot: 16 nodes/block, 4 nodes/wave; per node: 4 edge-slots x 4 feature-chunks
        int bid = blockIdx.x - NM/32;
        int wv = tid >> 6, l = tid & 63;
        int nd = l >> 4;          // node within wave
        int slot = (l >> 2) & 3;  // edge slot
        int chunk = l & 3;        // 8-half feature chunk
        int node = (bid << 4) + (wv << 2) + nd;
        unsigned pk = (unsigned)protRP[node];
        int s0 = (int)(pk & 0x1FFFFFu);
        int deg = (int)(pk >> 21);
        float edv = ed_[node];
        float selfw = __expf(leaky(es[node] + edv));
        float acc[8] = {0.f,0.f,0.f,0.f,0.f,0.f,0.f,0.f};
        float den = (slot == 0) ? selfw : 0.f;
        if (slot == 0) {
            H8 r; r.f4 = *(const float4*)&x32[(size_t)node * 32 + (chunk << 3)];
            #pragma unroll
            for (int i = 0; i < 4; i++) {
                float2 f = __half22float2(r.h2[i]);
                acc[2*i] = selfw * f.x; acc[2*i+1] = selfw * f.y;
            }
        }
        for (int base = 0; base < deg; base += 4) {
            int s = base + slot;
            int c = protCOL[s0 + s];
            bool vv = s < deg;
            int u = vv ? c : node;
            float w = vv ? __expf(leaky(es[u] + edv)) : 0.f;
            H8 r; r.f4 = *(const float4*)&x32[(size_t)u * 32 + (chunk << 3)];
            #pragma unroll
            for (int i = 0; i < 4; i++) {
                float2 f = __half22float2(r.h2[i]);
                acc[2*i] += w * f.x; acc[2*i+1] += w * f.y;
            }
            den += w;
        }
        #pragma unroll
        for (int m = 4; m <= 8; m <<= 1) {
            #pragma unroll
            for (int i = 0; i < 8; i++) acc[i] += __shfl_xor(acc[i], m, 64);
            den += __shfl_xor(den, m, 64);
        }
        float inv = 1.f / den;
        if (slot == 0) {
            float4 v0 = make_float4(acc[0]*inv, acc[1]*inv, acc[2]*inv, acc[3]*inv);
            if (chunk < 2) {
                float4 v1 = make_float4(acc[4]*inv, acc[5]*inv, acc[6]*inv, acc[7]*inv);
                *(float4*)&aggP[(size_t)node * 20 + (chunk << 3)]     = v0;
                *(float4*)&aggP[(size_t)node * 20 + (chunk << 3) + 4] = v1;
            } else if (chunk == 2) {
                *(float4*)&aggP[(size_t)node * 20 + 16] = v0;
            }
        }
    }
}

// ================= merged MLP via MFMA (f16 16x16x32), 64 nodes/block, 4 waves =================
// LDS (halves): W1T [64][40] @0, W2T [64][72] @2560, Ain [4][16][40] @7168, X1 [4][16][72] @9728
// Fragment layouts (HW-verified, learn_hip m89/m91):
//   A: row=lane&15, k=8*(lane>>4)+j (contiguous 16B)  B: col=lane&15, same k
//   D: col=lane&15, row=4*(lane>>4)+r
template<int D, int ATT, int SCALE>
__device__ __forceinline__ void mlp_mfma(__half* smemh, int bid, int tid,
                                         const float* __restrict__ agg, const float* __restrict__ W1,
                                         const float* __restrict__ b1, const float* __restrict__ W2,
                                         const float* __restrict__ as_, const float* __restrict__ ad_,
                                         __half* __restrict__ hout, float* __restrict__ es,
                                         float* __restrict__ ed_, const float* __restrict__ dinv,
                                         int n){
    __half* W1Ts = smemh;            // 64*40 = 2560 halves (k in [32,40) never read)
    __half* W2Ts = smemh + 2560;     // 64*72 = 4608 halves (k in [64,72) never read)
    __half* AinS = smemh + 7168;     // 4 waves * 16 rows * 40 k
    __half* X1S  = smemh + 9728;     // 4 waves * 16 rows * 72 cols
    int lane = tid & 63, w = tid >> 6;
    int c = lane & 15, g = lane >> 4;
    int node0 = bid * 64 + w * 16;

    // ---- stage transposed f16 weights (whole block, coalesced reads) ----
    for (int idx = tid; idx < 2048; idx += 256) {
        int k = idx >> 6, col = idx & 63;
        W1Ts[col * 40 + k] = __float2half(k < D ? W1[k * 64 + col] : 0.f);
    }
    for (int idx = tid; idx < 4096; idx += 256) {
        int k = idx >> 6, col = idx & 63;
        W2Ts[col * 72 + k] = __float2half(W2[k * 64 + col]);
    }
    // ---- zero + stage A rows (per wave, coalesced: rows are consecutive nodes) ----
    {
        float4 z4 = make_float4(0.f, 0.f, 0.f, 0.f);
        float4* az = (float4*)(AinS + w * 640);
        for (int i = lane; i < 80; i += 64) az[i] = z4;
        int lim = 16 * D;
        if (ATT) { int rem = n - node0; if (rem < 0) rem = 0; if (rem < 16) lim = rem * D; }
        const float* aw = agg + (size_t)node0 * D;
        for (int idx = lane; idx < lim; idx += 64) {
            int r = idx / D, k = idx - r * D;
            AinS[w * 640 + r * 40 + k] = __float2half(aw[idx]);
        }
    }
    __syncthreads();

    // ---- layer 1: [16 x K<=32] @ [K x 64] -> bias + relu -> X1 in LDS ----
    f32x4 zz = {0.f, 0.f, 0.f, 0.f};
    f16x8 a1 = *(const f16x8*)&AinS[w * 640 + c * 40 + 8 * g];
    #pragma unroll
    for (int t = 0; t < 4; t++) {
        f16x8 b = *(const f16x8*)&W1Ts[(16 * t + c) * 40 + 8 * g];
        f32x4 h = __builtin_amdgcn_mfma_f32_16x16x32_f16(a1, b, zz, 0, 0, 0);
        float bv = b1[16 * t + c];
        #pragma unroll
        for (int r = 0; r < 4; r++) {
            float v = fmaxf(h[r] + bv, 0.f);
            X1S[w * 1152 + (4 * g + r) * 72 + 16 * t + c] = __float2half(v);
        }
    }
    __syncthreads();

    // ---- layer 2: [16 x 64] @ [64 x 64] ----
    f32x4 acc[4];
    #pragma unroll
    for (int t = 0; t < 4; t++) acc[t] = zz;
    #pragma unroll
    for (int kt = 0; kt < 2; kt++) {
        f16x8 a = *(const f16x8*)&X1S[w * 1152 + c * 72 + 32 * kt + 8 * g];
        #pragma unroll
        for (int t = 0; t < 4; t++) {
            f16x8 b = *(const f16x8*)&W2Ts[(16 * t + c) * 72 + 32 * kt + 8 * g];
            acc[t] = __builtin_amdgcn_mfma_f32_16x16x32_f16(a, b, acc[t], 0, 0, 0);
        }
    }

    // ---- attention dots (prot): reduce row over 16 col-lanes ----
    if (ATT) {
        float asv[4], adv[4];
        #pragma unroll
        for (int t = 0; t < 4; t++) { asv[t] = as_[16 * t + c]; adv[t] = ad_[16 * t + c]; }
        #pragma unroll
        for (int r = 0; r < 4; r++) {
            float xa = 0.f, ya = 0.f;
            #pragma unroll
            for (int t = 0; t < 4; t++) { xa += acc[t][r] * asv[t]; ya += acc[t][r] * adv[t]; }
            #pragma unroll
            for (int m = 1; m < 16; m <<= 1) { xa += __shfl_xor(xa, m, 16); ya += __shfl_xor(ya, m, 16); }
            int nd = node0 + 4 * g + r;
            if (c == 0 && nd < n) { es[nd] = xa; ed_[nd] = ya; }
        }
    }
    // ---- pre-scale by dinv (mol) ----
    if (SCALE) {
        #pragma unroll
        for (int r = 0; r < 4; r++) {
            float dd = dinv[node0 + 4 * g + r];
            #pragma unroll
            for (int t = 0; t < 4; t++) acc[t][r] *= dd;
        }
    }

    // ---- repack through LDS (reuse X1 slab) -> coalesced float4 f16 stores ----
    #pragma unroll
    for (int t = 0; t < 4; t++) {
        #pragma unroll
        for (int r = 0; r < 4; r++)
            X1S[w * 1152 + (4 * g + r) * 72 + 16 * t + c] = __float2half(acc[t][r]);
    }
    __syncthreads();
    int rr = lane >> 2, seg = lane & 3;
    union { f16x8 h; float4 f; } o;
    o.h = *(const f16x8*)&X1S[w * 1152 + rr * 72 + seg * 16];
    int nd = node0 + rr;
    if (!ATT || nd < n)
        *(float4*)&hout[(size_t)nd * 64 + seg * 16] = o.f;
}

__global__ void k_mlp2(const float* __restrict__ aggM, const float* __restrict__ gcn_w1,
                       const float* __restrict__ gcn_b1, const float* __restrict__ gcn_w2,
                       __half* __restrict__ h2hM, const float* __restrict__ dinvM,
                       const float* __restrict__ aggP, const float* __restrict__ gat_w1,
                       const float* __restrict__ gat_b1, const float* __restrict__ gat_w2,
                       const float* __restrict__ as2, const float* __restrict__ ad2,
                       __half* __restrict__ h2hP, float* __restrict__ es, float* __restrict__ ed_){
    __shared__ __attribute__((aligned(16))) __half smemh[14336];   // 28672 B -> 5 blocks/CU
    if (blockIdx.x < NM/64)
        mlp_mfma<6, 0, 1>(smemh, blockIdx.x, threadIdx.x, aggM, gcn_w1, gcn_b1, gcn_w2,
                          nullptr, nullptr, h2hM, nullptr, nullptr, dinvM, NM);
    else
        mlp_mfma<20, 1, 0>(smemh, blockIdx.x - NM/64, threadIdx.x, aggP, gat_w1, gat_b1, gat_w2,
                           as2, ad2, h2hP, es, ed_, nullptr, NP);
}

// ---------------- prot layer-2 gather: 8 groups x 8 lanes, 2 slots/group, fp16 out ----------------
__global__ void k_gather64h_gat(const int* __restrict__ rp, const int* __restrict__ col,
                                const __half* __restrict__ hh, const float* __restrict__ es,
                                const float* __restrict__ ed_, const float* __restrict__ b,
                                __half* __restrict__ out_h){
    int tid = threadIdx.x;
    int node = (blockIdx.x << 2) + (tid >> 6);
    int l = tid & 63, g = l >> 3, q = l & 7;
    unsigned pk = (unsigned)rp[node];
    int s0 = (int)(pk & 0x1FFFFFu);
    int deg = (int)(pk >> 21);
    float edv = ed_[node];
    float selfw = __expf(leaky(es[node] + edv));
    float acc[8] = {0.f,0.f,0.f,0.f,0.f,0.f,0.f,0.f};
    float den = (l == 0) ? selfw : 0.f;
    if (g == 0) {
        H8 r; r.f4 = *(const float4*)&hh[(size_t)node * 64 + (q << 3)];
        #pragma unroll
        for (int i = 0; i < 4; i++) {
            float2 f = __half22float2(r.h2[i]);
            acc[2*i]     = selfw * f.x;
            acc[2*i + 1] = selfw * f.y;
        }
    }
    for (int base = 0; base < deg; base += 16) {
        int sA = base + g, sB = base + g + 8;
        int cA = col[s0 + sA], cB = col[s0 + sB];
        int uA = (sA < deg) ? cA : node;
        int uB = (sB < deg) ? cB : node;
        float eA = es[uA], eB = es[uB];
        float wA = (sA < deg) ? __expf(leaky(eA + edv)) : 0.f;
        float wB = (sB < deg) ? __expf(leaky(eB + edv)) : 0.f;
        H8 rA, rB;
        rA.f4 = *(const float4*)&hh[(size_t)uA * 64 + (q << 3)];
        rB.f4 = *(const float4*)&hh[(size_t)uB * 64 + (q << 3)];
        #pragma unroll
        for (int i = 0; i < 4; i++) {
            float2 fA = __half22float2(rA.h2[i]);
            float2 fB = __half22float2(rB.h2[i]);
            acc[2*i]     += wA * fA.x + wB * fB.x;
            acc[2*i + 1] += wA * fA.y + wB * fB.y;
        }
        if (q == 0) den += wA + wB;
    }
    #pragma unroll
    for (int m = 8; m <= 32; m <<= 1) {
        #pragma unroll
        for (int i = 0; i < 8; i++) acc[i] += __shfl_xor(acc[i], m, 64);
        den += __shfl_xor(den, m, 64);
    }
    den = __shfl(den, 0, 64);
    if (g == 0) {
        float sc = 1.f / den;
        int f = q << 3;
        H8 o;
        #pragma unroll
        for (int i = 0; i < 4; i++)
            o.h2[i] = __floats2half2_rn(acc[2*i]*sc + b[f + 2*i], acc[2*i+1]*sc + b[f + 2*i + 1]);
        *(float4*)&out_h[(size_t)node * 64 + f] = o.f4;
    }
}

// ---------------- mol layer-2 gather: 8 slots x 8 lanes, pre-scaled rows, fp16 out ----------------
__global__ void k_gather64h_gcn(const int* __restrict__ rp, const int* __restrict__ col,
                                const __half* __restrict__ hh, const float* __restrict__ dinv,
                                const float* __restrict__ b, __half* __restrict__ out_h){
    int tid = threadIdx.x;
    int node = (blockIdx.x << 2) + (tid >> 6);
    int l = tid & 63, g = l >> 3, q = l & 7;
    unsigned pk = (unsigned)rp[node];
    int s0 = (int)(pk & 0xFFFFFu);
    int deg = (int)(pk >> 20);
    float acc[8] = {0.f,0.f,0.f,0.f,0.f,0.f,0.f,0.f};
    if (g == 0) {
        H8 r; r.f4 = *(const float4*)&hh[(size_t)node * 64 + (q << 3)];
        #pragma unroll
        for (int i = 0; i < 4; i++) {
            float2 f = __half22float2(r.h2[i]);
            acc[2*i]     = f.x;
            acc[2*i + 1] = f.y;
        }
    }
    for (int base = 0; base < deg; base += 8) {
        int s = base + g;
        int c = col[s0 + s];
        int u = (s < deg) ? c : node;
        float wvv = (s < deg) ? 1.f : 0.f;
        H8 r; r.f4 = *(const float4*)&hh[(size_t)u * 64 + (q << 3)];
        #pragma unroll
        for (int i = 0; i < 4; i++) {
            float2 f = __half22float2(r.h2[i]);
            acc[2*i]     += wvv * f.x;
            acc[2*i + 1] += wvv * f.y;
        }
    }
    #pragma unroll
    for (int m = 8; m <= 32; m <<= 1) {
        #pragma unroll
        for (int i = 0; i < 8; i++) acc[i] += __shfl_xor(acc[i], m, 64);
    }
    if (g == 0) {
        float sc = dinv[node];
        int f = q << 3;
        H8 o;
        #pragma unroll
        for (int i = 0; i < 4; i++)
            o.h2[i] = __floats2half2_rn(acc[2*i]*sc + b[f + 2*i], acc[2*i+1]*sc + b[f + 2*i + 1]);
        *(float4*)&out_h[(size_t)node * 64 + f] = o.f4;
    }
}

// ================= merged pools: segpool fp16 (1024 blocks) + prot pool fp16 (1024) =================
__global__ void k_pool2(const int* __restrict__ gstart, const int* __restrict__ gend,
                        const __half* __restrict__ molout_h, float* __restrict__ gsum,
                        const __half* __restrict__ protout_h, float* __restrict__ psum){
    __shared__ float red[4][64];
    int t = threadIdx.x;
    if (blockIdx.x < 1024) {
        // 4 graphs per block, one wave each
        int wv = t >> 6, l = t & 63, rg = l >> 4, q = l & 15;
        int gph = (blockIdx.x << 2) + wv;
        int s = gstart[gph], c = gend[gph] - gstart[gph];
        float4 a = {0.f, 0.f, 0.f, 0.f};
        for (int i = rg; i < c; i += 4) {
            __half2 h0 = *(const __half2*)&molout_h[(size_t)(s + i) * 64 + (q << 2)];
            __half2 h1 = *(const __half2*)&molout_h[(size_t)(s + i) * 64 + (q << 2) + 2];
            float2 f0 = __half22float2(h0), f1 = __half22float2(h1);
            a.x += f0.x; a.y += f0.y; a.z += f1.x; a.w += f1.y;
        }
        #pragma unroll
        for (int m = 16; m <= 32; m <<= 1) {
            a.x += __shfl_xor(a.x, m, 64);
            a.y += __shfl_xor(a.y, m, 64);
            a.z += __shfl_xor(a.z, m, 64);
            a.w += __shfl_xor(a.w, m, 64);
        }
        if (rg == 0) *(float4*)&gsum[gph * 64 + (q << 2)] = a;
    } else {
        // grid-stride over NP*8 chunks of 8 halves; phase = chunk & 7
        const float4* p4 = (const float4*)protout_h;
        const int TC = NP * 8;
        float acc[8] = {0.f,0.f,0.f,0.f,0.f,0.f,0.f,0.f};
        for (int i = (blockIdx.x - 1024) * 256 + t; i < TC; i += 1024 * 256) {
            H8 r; r.f4 = p4[i];
            #pragma unroll
            for (int j = 0; j < 4; j++) {
                float2 f = __half22float2(r.h2[j]);
                acc[2*j] += f.x; acc[2*j+1] += f.y;
            }
        }
        int lane = t & 63, wv = t >> 6;
        #pragma unroll
        for (int m = 8; m <= 32; m <<= 1) {
            #pragma unroll
            for (int j = 0; j < 8; j++) acc[j] += __shfl_xor(acc[j], m, 64);
        }
        if (lane < 8) {
            #pragma unroll
            for (int j = 0; j < 8; j++) red[wv][lane * 8 + j] = acc[j];
        }
        __syncthreads();
        if (t < 64) {
            float s = red[0][t] + red[1][t] + red[2][t] + red[3][t];
            atomicAdd(&psum[t], s);
        }
    }
}

// ---------------- fused classifier ----------------
__global__ void k_cls(const float* __restrict__ gsum, const int* __restrict__ gstart,
                      const int* __restrict__ gend, const float* __restrict__ psum,
                      const float* __restrict__ W1, const float* __restrict__ b1,
                      const float* __restrict__ w2, const float* __restrict__ b2,
                      float* __restrict__ out){
    __shared__ float W1s[128 * 64];
    int tid = threadIdx.x;
    for (int k = tid; k < 128 * 64; k += 256) W1s[k] = W1[k];
    __syncthreads();
    int g = blockIdx.x * 4 + (tid >> 6);
    int j = tid & 63;
    float cntf = (float)(gend[g] - gstart[g]);
    float inv = 1.0f / fmaxf(cntf, 1.0f);
    const float invp = 1.0f / (float)NP;
    float acc = b1[j];
    #pragma unroll 8
    for (int k = 0; k < 64; k++) acc += (gsum[g * 64 + k] * inv) * W1s[k * 64 + j];
    #pragma unroll 8
    for (int k = 0; k < 64; k++) acc += (psum[k] * invp) * W1s[(64 + k) * 64 + j];
    float v = fmaxf(acc, 0.f) * w2[j];
    #pragma unroll
    for (int off = 32; off > 0; off >>= 1) v += __shfl_down(v, off, 64);
    if (j == 0) out[g] = 1.0f / (1.0f + expf(-(v + b2[0])));
}

extern "C" void kernel_launch(void* const* d_in, const int* in_sizes, int n_in,
                              void* d_out, int out_size, void* d_ws, size_t ws_size,
                              hipStream_t stream) {
    const float* mol_x   = (const float*)d_in[0];
    const int*   mol_ei  = (const int*)d_in[1];
    const int*   mol_bat = (const int*)d_in[2];
    const float* prot_x  = (const float*)d_in[3];
    const int*   prot_ei = (const int*)d_in[4];
    const float* gcn_w1  = (const float*)d_in[5];
    const float* gcn_b1  = (const float*)d_in[6];
    const float* gcn_w2  = (const float*)d_in[7];
    const float* gcn_b2  = (const float*)d_in[8];
    const float* gat_w1  = (const float*)d_in[9];
    const float* gat_as1 = (const float*)d_in[10];
    const float* gat_ad1 = (const float*)d_in[11];
    const float* gat_b1  = (const float*)d_in[12];
    const float* gat_w2  = (const float*)d_in[13];
    const float* gat_as2 = (const float*)d_in[14];
    const float* gat_ad2 = (const float*)d_in[15];
    const float* gat_b2  = (const float*)d_in[16];
    const float* cls_w1  = (const float*)d_in[17];
    const float* cls_b1  = (const float*)d_in[18];
    const float* cls_w2  = (const float*)d_in[19];
    const float* cls_b2  = (const float*)d_in[20];
    float* out = (float*)d_out;

    float* ws_f = (float*)d_ws;

    // ---- persistent tail; [gstart .. coarseP+512) is one contiguous zeroed region ----
    float* T       = ws_f + 16777216;
    float* gsum    = T;                       // 262,144 floats (no init needed)
    int*   gstart  = (int*)(T + 262144);      // 4,096 ints (zeroed)
    int*   gend    = (int*)(T + 266240);      // 4,096 ints (zeroed)
    float* psum    = T + 270336;              // 64 floats (zeroed)
    int*   coarseM = (int*)(T + 270400);      // 512 ints (zeroed)
    int*   coarseP = (int*)(T + 270912);      // 512 ints (zeroed)
    int*   cstartM = (int*)(T + 271424);      // 513
    int*   cursorM = (int*)(T + 271937);      // 512
    int*   cstartP = (int*)(T + 272449);      // 513
    int*   cursorP = (int*)(T + 272962);      // 512

    // ---- early CSR staging (dead after k_fine2) ----
    unsigned* bufM = (unsigned*)ws_f;                    // [0, 524,288)
    unsigned* bufP = (unsigned*)(ws_f + 524352);         // [524,352, 2,124,416)

    // ---- overlapping phase regions (all offsets in floats) ----
    __half*   h2hP      = (__half*)ws_f;
    __half*   molout_h  = (__half*)ws_f;
    __half*   x32h      = (__half*)(ws_f + 4194304);
    __half*   protout_h = (__half*)(ws_f + 4194304);
    float*    aggP      = ws_f + 5794304;
    float*    es        = ws_f + 7794304;
    float*    ed_       = ws_f + 7894304;
    __half*   h2hM      = (__half*)(ws_f + 8388608);
    int*      molCOL    = (int*)(ws_f + 12582912);       // EM+64 -> 13,107,264
    int*      molRP     = (int*)(ws_f + 13107264);       // NM -> 13,238,336 (+pad)
    float*    dinvM     = ws_f + 13238352;               // NM -> 13,369,424 (+pad)
    __half*   x8h       = (__half*)(ws_f + 13369440);    // NM*8 halves -> 13,893,728 (+pad)
    float*    aggM      = ws_f + 13893792;               // NM*6 -> 14,680,224 (+pad)
    int*      protCOL   = (int*)(ws_f + 14680256);       // EP+64 -> 16,280,320
    int*      protRP    = (int*)(ws_f + 16280320);       // NP -> 16,380,320

    // single upfront zero of gstart+gend+psum+coarseM+coarseP (contiguous)
    (void)hipMemsetAsync(gstart, 0, (size_t)(4096 + 4096 + 64 + 512 + 512) * sizeof(int), stream);

    // ================= merged CSR build (mol + prot) =================
    k_hist2<<<256 + 391, 256, 0, stream>>>(mol_ei + EM, prot_ei + EP, coarseM, coarseP);
    k_scan2<<<2, 512, 0, stream>>>(coarseM, cstartM, cursorM, coarseP, cstartP, cursorP);
    k_part2<<<128 + 391, 256, 0, stream>>>(mol_ei, cursorM, bufM, prot_ei, cursorP, bufP);
    k_fine2<<<512 + 391, 256, 0, stream>>>(bufM, cstartM, molRP, molCOL, dinvM,
                                           bufP, cstartP, protRP, protCOL);

    // ================= merged preps =================
    k_prep2<<<512 + 512 + 391, 256, 0, stream>>>(mol_x, dinvM, x8h, mol_bat, gstart, gend,
                                                 prot_x, gat_w1, gat_as1, gat_ad1, x32h, es, ed_);

    // ================= merged L1 gathers (prot: 16 nodes/block) =================
    k_l1g2<<<NM/32 + NP/16, 256, 0, stream>>>(molRP, molCOL, x8h, dinvM, aggM,
                                              protRP, protCOL, x32h, es, ed_, aggP);

    // ================= merged MLPs (MFMA, 64 nodes/block) =================
    k_mlp2<<<NM/64 + cdiv(NP, 64), 256, 0, stream>>>(aggM, gcn_w1, gcn_b1, gcn_w2, h2hM, dinvM,
                                                     aggP, gat_w1, gat_b1, gat_w2, gat_as2, gat_ad2,
                                                     h2hP, es, ed_);

    // ================= L2 gathers (gat first: gcn's molout_h overwrites h2hP) =================
    k_gather64h_gat<<<NP/4, 256, 0, stream>>>(protRP, protCOL, h2hP, es, ed_, gat_b2, protout_h);
    k_gather64h_gcn<<<NM/4, 256, 0, stream>>>(molRP, molCOL, h2hM, dinvM, gcn_b2, molout_h);

    // ================= merged pools =================
    k_pool2<<<1024 + 1024, 256, 0, stream>>>(gstart, gend, molout_h, gsum, protout_h, psum);

    // ================= classifier =================
    k_cls<<<NG/4, 256, 0, stream>>>(gsum, gstart, gend, psum, cls_w1, cls_b1, cls_w2, cls_b2, out);
}

// Round 3
// 335.094 us; speedup vs baseline: 1.2122x; 1.0679x over previous
//
#include <hip/hip_runtime.h>
#include <hip/hip_fp16.h>

#define NM 131072   // mol nodes
#define EM 524288   // mol edges
#define NG 4096     // graphs
#define DM 6        // mol in dim
#define NP 100000   // prot nodes
#define EP 1600000  // prot edges
#define DP 20       // prot in dim

static inline int cdiv(int a, int b){ return (a + b - 1) / b; }

__device__ __forceinline__ float leaky(float x){ return x > 0.f ? x : 0.2f * x; }

union H8 { float4 f4; __half2 h2[4]; };

typedef _Float16 f16x8 __attribute__((ext_vector_type(8)));
typedef float    f32x4 __attribute__((ext_vector_type(4)));

// ================= merged bucketed CSR build (round-16, proven) =================
__global__ void k_hist2(const int* __restrict__ dstM, const int* __restrict__ dstP,
                        int* __restrict__ coarseM, int* __restrict__ coarseP){
    __shared__ int lh[512];
    int t = threadIdx.x;
    const int* dst; int* coarse; int K, E, base, chunk;
    if (blockIdx.x < 256) { dst = dstM; coarse = coarseM; K = 512; E = EM; chunk = 2048; base = blockIdx.x * 2048; }
    else                  { dst = dstP; coarse = coarseP; K = 391; E = EP; chunk = 4096; base = (blockIdx.x - 256) * 4096; }
    for (int i = t; i < K; i += 256) lh[i] = 0;
    __syncthreads();
    int end = min(base + chunk, E);
    for (int e = base + t; e < end; e += 256)
        atomicAdd(&lh[dst[e] >> 8], 1);
    __syncthreads();
    for (int i = t; i < K; i += 256)
        if (lh[i]) atomicAdd(&coarse[i], lh[i]);
}

__global__ void k_scan2(const int* __restrict__ coarseM, int* __restrict__ cstartM, int* __restrict__ cursorM,
                        const int* __restrict__ coarseP, int* __restrict__ cstartP, int* __restrict__ cursorP){
    const int* coarse; int* cstart; int* cursor; int K;
    if (blockIdx.x == 0) { coarse = coarseM; cstart = cstartM; cursor = cursorM; K = 512; }
    else                 { coarse = coarseP; cstart = cstartP; cursor = cursorP; K = 391; }
    int t = threadIdx.x, lane = t & 63, wid = t >> 6;
    int v0 = (t < K) ? coarse[t] : 0;
    int v = v0;
    #pragma unroll
    for (int off = 1; off < 64; off <<= 1) {
        int x = __shfl_up(v, off, 64);
        if (lane >= off) v += x;
    }
    __shared__ int ws[8];
    if (lane == 63) ws[wid] = v;
    __syncthreads();
    int add = 0;
    for (int w = 0; w < wid; w++) add += ws[w];
    int excl = v + add - v0;
    if (t < K) { cstart[t] = excl; cursor[t] = excl; }
    if (t == K - 1) cstart[K] = excl + v0;
}

__global__ void k_part2(const int* __restrict__ eiM, int* __restrict__ cursorM, unsigned* __restrict__ bufM,
                        const int* __restrict__ eiP, int* __restrict__ cursorP, unsigned* __restrict__ bufP){
    __shared__ int lh[512];
    __shared__ int lbase[512];
    const int* ei; int* cursor; unsigned* buf; int E, K, base;
    if (blockIdx.x < 128) { ei = eiM; cursor = cursorM; buf = bufM; E = EM; K = 512; base = blockIdx.x * 4096; }
    else                  { ei = eiP; cursor = cursorP; buf = bufP; E = EP; K = 391; base = (blockIdx.x - 128) * 4096; }
    int t = threadIdx.x;
    for (int i = t; i < K; i += 256) lh[i] = 0;
    __syncthreads();
    int end = min(base + 4096, E);
    unsigned pay[16]; int bslot[16];
    int cnt = 0;
    for (int e = base + t; e < end; e += 256) {
        int u = ei[e], v = ei[E + e];
        int b = v >> 8;
        int ls = atomicAdd(&lh[b], 1);
        pay[cnt] = ((unsigned)(v & 255) << 24) | (unsigned)u;
        bslot[cnt] = (b << 13) | ls;
        cnt++;
    }
    __syncthreads();
    for (int i = t; i < K; i += 256)
        lbase[i] = lh[i] ? atomicAdd(&cursor[i], lh[i]) : 0;
    __syncthreads();
    for (int j = 0; j < cnt; j++) {
        int b = bslot[j] >> 13, ls = bslot[j] & 8191;
        buf[lbase[b] + ls] = pay[j];
    }
}

__global__ void k_fine2(const unsigned* __restrict__ bufM, const int* __restrict__ cstartM,
                        int* __restrict__ molRP, int* __restrict__ molCOL, float* __restrict__ dinv,
                        const unsigned* __restrict__ bufP, const int* __restrict__ cstartP,
                        int* __restrict__ protRP, int* __restrict__ protCOL){
    int t = threadIdx.x;
    int k; const unsigned* buf; const int* cstart; int* rp; int* col; int n, OB, dv;
    if (blockIdx.x < 512) { k = blockIdx.x;       buf = bufM; cstart = cstartM; rp = molRP;  col = molCOL;  n = NM; OB = 20; dv = 1; }
    else                  { k = blockIdx.x - 512; buf = bufP; cstart = cstartP; rp = protRP; col = protCOL; n = NP; OB = 21; dv = 0; }
    int start = cstart[k], end = cstart[k + 1];
    __shared__ int cnt[256];
    __shared__ int cur[256];
    cnt[t] = 0;
    __syncthreads();
    for (int p = start + t; p < end; p += 256)
        atomicAdd(&cnt[buf[p] >> 24], 1);
    __syncthreads();
    int v0 = cnt[t];
    int lane = t & 63, wid = t >> 6;
    int v = v0;
    #pragma unroll
    for (int off = 1; off < 64; off <<= 1) {
        int x = __shfl_up(v, off, 64);
        if (lane >= off) v += x;
    }
    __shared__ int ws[4];
    if (lane == 63) ws[wid] = v;
    __syncthreads();
    int add = 0;
    for (int w = 0; w < wid; w++) add += ws[w];
    int excl = v + add - v0;
    int ofs = start + excl;
    cur[t] = ofs;
    int idx = (k << 8) + t;
    if (idx < n) {
        rp[idx] = (int)((unsigned)ofs | ((unsigned)v0 << OB));
        if (dv) dinv[idx] = rsqrtf((float)(v0 + 1));
    }
    __syncthreads();
    for (int p = start + t; p < end; p += 256) {
        unsigned pk = buf[p];
        int slot = atomicAdd(&cur[pk >> 24], 1);
        col[slot] = (int)(pk & 0xFFFFFFu);
    }
}

// ================= merged prep: molprep (512) + segbounds (512) + prot prep (391) =================
__global__ void k_prep2(const float* __restrict__ mol_x, const float* __restrict__ dinv,
                        __half* __restrict__ x8, const int* __restrict__ batch,
                        int* __restrict__ gstart, int* __restrict__ gend,
                        const float* __restrict__ prot_x, const float* __restrict__ W1,
                        const float* __restrict__ as_, const float* __restrict__ ad_,
                        __half* __restrict__ x32, float* __restrict__ es,
                        float* __restrict__ ed_){
    __shared__ float vas[20], vds[20];
    int b = blockIdx.x, t = threadIdx.x;
    if (b < 512) {
        int i = b * 256 + t;
        float dd = dinv[i];
        H8 r;
        #pragma unroll
        for (int k = 0; k < 3; k++)
            r.h2[k] = __floats2half2_rn(dd * mol_x[i*6 + 2*k], dd * mol_x[i*6 + 2*k + 1]);
        r.h2[3] = __floats2half2_rn(0.f, 0.f);
        *(float4*)&x8[(size_t)i * 8] = r.f4;
    } else if (b < 1024) {
        int i = (b - 512) * 256 + t;
        int g = batch[i];
        if (i == 0 || batch[i - 1] != g) gstart[g] = i;
        if (i == NM - 1 || batch[i + 1] != g) gend[g] = i + 1;
    } else {
        if (t < 20) {
            float s = 0.f;
            for (int j = 0; j < 64; j++) s += W1[t * 64 + j] * as_[j];
            vas[t] = s;
        } else if (t >= 32 && t < 52) {
            int k = t - 32;
            float s = 0.f;
            for (int j = 0; j < 64; j++) s += W1[k * 64 + j] * ad_[j];
            vds[k] = s;
        }
        __syncthreads();
        int i = (b - 1024) * 256 + t;
        if (i >= NP) return;
        float xv[20];
        float s = 0.f, d = 0.f;
        #pragma unroll
        for (int k = 0; k < 20; k++) {
            xv[k] = prot_x[i*20 + k];
            s += xv[k] * vas[k]; d += xv[k] * vds[k];
        }
        es[i] = s; ed_[i] = d;
        H8 r0, r1, r2, rz;
        #pragma unroll
        for (int k = 0; k < 4; k++) r0.h2[k] = __floats2half2_rn(xv[2*k],   xv[2*k+1]);
        #pragma unroll
        for (int k = 0; k < 4; k++) r1.h2[k] = __floats2half2_rn(xv[8+2*k], xv[9+2*k]);
        r2.h2[0] = __floats2half2_rn(xv[16], xv[17]);
        r2.h2[1] = __floats2half2_rn(xv[18], xv[19]);
        r2.h2[2] = __floats2half2_rn(0.f, 0.f);
        r2.h2[3] = __floats2half2_rn(0.f, 0.f);
        rz.h2[0] = rz.h2[1] = rz.h2[2] = rz.h2[3] = __floats2half2_rn(0.f, 0.f);
        *(float4*)&x32[(size_t)i * 32]      = r0.f4;
        *(float4*)&x32[(size_t)i * 32 + 8]  = r1.f4;
        *(float4*)&x32[(size_t)i * 32 + 16] = r2.f4;
        *(float4*)&x32[(size_t)i * 32 + 24] = rz.f4;
    }
}

// ================= merged L1 gathers: mol (4096 blocks) + prot (6250 blocks, 4 nodes/wave) =================
__global__ void k_l1g2(const int* __restrict__ molRP, const int* __restrict__ molCOL,
                       const __half* __restrict__ x8, const float* __restrict__ dinv,
                       float* __restrict__ aggM,
                       const int* __restrict__ protRP, const int* __restrict__ protCOL,
                       const __half* __restrict__ x32, const float* __restrict__ es,
                       const float* __restrict__ ed_, float* __restrict__ aggP){
    __shared__ float ost[192];
    int tid = threadIdx.x;
    if (blockIdx.x < NM/32) {
        int bid = blockIdx.x;
        int wv = tid >> 6, l = tid & 63, g = l >> 3, q = l & 7;
        int node = (bid << 5) + (wv << 3) + g;
        unsigned pk = (unsigned)molRP[node];
        int s0 = (int)(pk & 0xFFFFFu);
        int deg = (int)(pk >> 20);
        float acc[6] = {0.f,0.f,0.f,0.f,0.f,0.f};
        if (q == 0) {
            H8 r; r.f4 = *(const float4*)&x8[(size_t)node * 8];
            #pragma unroll
            for (int i = 0; i < 3; i++) {
                float2 f = __half22float2(r.h2[i]);
                acc[2*i] = f.x; acc[2*i+1] = f.y;
            }
        }
        for (int base = 0; base < deg; base += 8) {
            int s = base + q;
            int c = molCOL[s0 + s];
            int u = (s < deg) ? c : node;
            float wvv = (s < deg) ? 1.f : 0.f;
            H8 r; r.f4 = *(const float4*)&x8[(size_t)u * 8];
            #pragma unroll
            for (int i = 0; i < 3; i++) {
                float2 f = __half22float2(r.h2[i]);
                acc[2*i] += wvv * f.x; acc[2*i+1] += wvv * f.y;
            }
        }
        #pragma unroll
        for (int m = 1; m < 8; m <<= 1) {
            #pragma unroll
            for (int i = 0; i < 6; i++) acc[i] += __shfl_xor(acc[i], m, 8);
        }
        if (q == 0) {
            float dd = dinv[node];
            int slot = (wv << 3) + g;
            #pragma unroll
            for (int i = 0; i < 6; i++) ost[slot * 6 + i] = dd * acc[i];
        }
        __syncthreads();
        if (tid < 48)
            *(float4*)&aggM[(size_t)bid * 192 + (tid << 2)] = *(float4*)&ost[tid << 2];
    } else {
        // prot: 16 nodes/block, 4 nodes/wave; per node: 4 edge-slots x 4 feature-chunks
        int bid = blockIdx.x - NM/32;
        int wv = tid >> 6, l = tid & 63;
        int nd = l >> 4;          // node within wave
        int slot = (l >> 2) & 3;  // edge slot
        int chunk = l & 3;        // 8-half feature chunk
        int node = (bid << 4) + (wv << 2) + nd;
        unsigned pk = (unsigned)protRP[node];
        int s0 = (int)(pk & 0x1FFFFFu);
        int deg = (int)(pk >> 21);
        float edv = ed_[node];
        float selfw = __expf(leaky(es[node] + edv));
        float acc[8] = {0.f,0.f,0.f,0.f,0.f,0.f,0.f,0.f};
        float den = (slot == 0) ? selfw : 0.f;
        if (slot == 0) {
            H8 r; r.f4 = *(const float4*)&x32[(size_t)node * 32 + (chunk << 3)];
            #pragma unroll
            for (int i = 0; i < 4; i++) {
                float2 f = __half22float2(r.h2[i]);
                acc[2*i] = selfw * f.x; acc[2*i+1] = selfw * f.y;
            }
        }
        for (int base = 0; base < deg; base += 4) {
            int s = base + slot;
            int c = protCOL[s0 + s];
            bool vv = s < deg;
            int u = vv ? c : node;
            float w = vv ? __expf(leaky(es[u] + edv)) : 0.f;
            H8 r; r.f4 = *(const float4*)&x32[(size_t)u * 32 + (chunk << 3)];
            #pragma unroll
            for (int i = 0; i < 4; i++) {
                float2 f = __half22float2(r.h2[i]);
                acc[2*i] += w * f.x; acc[2*i+1] += w * f.y;
            }
            den += w;
        }
        #pragma unroll
        for (int m = 4; m <= 8; m <<= 1) {
            #pragma unroll
            for (int i = 0; i < 8; i++) acc[i] += __shfl_xor(acc[i], m, 64);
            den += __shfl_xor(den, m, 64);
        }
        float inv = 1.f / den;
        if (slot == 0) {
            float4 v0 = make_float4(acc[0]*inv, acc[1]*inv, acc[2]*inv, acc[3]*inv);
            if (chunk < 2) {
                float4 v1 = make_float4(acc[4]*inv, acc[5]*inv, acc[6]*inv, acc[7]*inv);
                *(float4*)&aggP[(size_t)node * 20 + (chunk << 3)]     = v0;
                *(float4*)&aggP[(size_t)node * 20 + (chunk << 3) + 4] = v1;
            } else if (chunk == 2) {
                *(float4*)&aggP[(size_t)node * 20 + 16] = v0;
            }
        }
    }
}

// ================= merged MLP via MFMA (f16 16x16x32), 64 nodes/block, 4 waves =================
// LDS (halves): W1T [64][40] @0, W2T [64][72] @2560, Ain [4][16][40] @7168, X1 [4][16][72] @9728
// Fragment layouts (HW-verified, learn_hip m89/m91):
//   A: row=lane&15, k=8*(lane>>4)+j (contiguous 16B)  B: col=lane&15, same k
//   D: col=lane&15, row=4*(lane>>4)+r
template<int D, int ATT, int SCALE>
__device__ __forceinline__ void mlp_mfma(__half* smemh, int bid, int tid,
                                         const float* __restrict__ agg, const float* __restrict__ W1,
                                         const float* __restrict__ b1, const float* __restrict__ W2,
                                         const float* __restrict__ as_, const float* __restrict__ ad_,
                                         __half* __restrict__ hout, float* __restrict__ es,
                                         float* __restrict__ ed_, const float* __restrict__ dinv,
                                         int n){
    __half* W1Ts = smemh;            // 64*40 = 2560 halves (k in [32,40) never read)
    __half* W2Ts = smemh + 2560;     // 64*72 = 4608 halves (k in [64,72) never read)
    __half* AinS = smemh + 7168;     // 4 waves * 16 rows * 40 k
    __half* X1S  = smemh + 9728;     // 4 waves * 16 rows * 72 cols
    int lane = tid & 63, w = tid >> 6;
    int c = lane & 15, g = lane >> 4;
    int node0 = bid * 64 + w * 16;

    // ---- stage transposed f16 weights (whole block, coalesced reads) ----
    for (int idx = tid; idx < 2048; idx += 256) {
        int k = idx >> 6, col = idx & 63;
        W1Ts[col * 40 + k] = __float2half(k < D ? W1[k * 64 + col] : 0.f);
    }
    for (int idx = tid; idx < 4096; idx += 256) {
        int k = idx >> 6, col = idx & 63;
        W2Ts[col * 72 + k] = __float2half(W2[k * 64 + col]);
    }
    // ---- zero + stage A rows (per wave, coalesced: rows are consecutive nodes) ----
    {
        float4 z4 = make_float4(0.f, 0.f, 0.f, 0.f);
        float4* az = (float4*)(AinS + w * 640);
        for (int i = lane; i < 80; i += 64) az[i] = z4;
        int lim = 16 * D;
        if (ATT) { int rem = n - node0; if (rem < 0) rem = 0; if (rem < 16) lim = rem * D; }
        const float* aw = agg + (size_t)node0 * D;
        for (int idx = lane; idx < lim; idx += 64) {
            int r = idx / D, k = idx - r * D;
            AinS[w * 640 + r * 40 + k] = __float2half(aw[idx]);
        }
    }
    __syncthreads();

    // ---- layer 1: [16 x K<=32] @ [K x 64] -> bias + relu -> X1 in LDS ----
    f32x4 zz = {0.f, 0.f, 0.f, 0.f};
    f16x8 a1 = *(const f16x8*)&AinS[w * 640 + c * 40 + 8 * g];
    #pragma unroll
    for (int t = 0; t < 4; t++) {
        f16x8 b = *(const f16x8*)&W1Ts[(16 * t + c) * 40 + 8 * g];
        f32x4 h = __builtin_amdgcn_mfma_f32_16x16x32_f16(a1, b, zz, 0, 0, 0);
        float bv = b1[16 * t + c];
        #pragma unroll
        for (int r = 0; r < 4; r++) {
            float v = fmaxf(h[r] + bv, 0.f);
            X1S[w * 1152 + (4 * g + r) * 72 + 16 * t + c] = __float2half(v);
        }
    }
    __syncthreads();

    // ---- layer 2: [16 x 64] @ [64 x 64] ----
    f32x4 acc[4];
    #pragma unroll
    for (int t = 0; t < 4; t++) acc[t] = zz;
    #pragma unroll
    for (int kt = 0; kt < 2; kt++) {
        f16x8 a = *(const f16x8*)&X1S[w * 1152 + c * 72 + 32 * kt + 8 * g];
        #pragma unroll
        for (int t = 0; t < 4; t++) {
            f16x8 b = *(const f16x8*)&W2Ts[(16 * t + c) * 72 + 32 * kt + 8 * g];
            acc[t] = __builtin_amdgcn_mfma_f32_16x16x32_f16(a, b, acc[t], 0, 0, 0);
        }
    }

    // ---- attention dots (prot): reduce row over 16 col-lanes ----
    if (ATT) {
        float asv[4], adv[4];
        #pragma unroll
        for (int t = 0; t < 4; t++) { asv[t] = as_[16 * t + c]; adv[t] = ad_[16 * t + c]; }
        #pragma unroll
        for (int r = 0; r < 4; r++) {
            float xa = 0.f, ya = 0.f;
            #pragma unroll
            for (int t = 0; t < 4; t++) { xa += acc[t][r] * asv[t]; ya += acc[t][r] * adv[t]; }
            #pragma unroll
            for (int m = 1; m < 16; m <<= 1) { xa += __shfl_xor(xa, m, 16); ya += __shfl_xor(ya, m, 16); }
            int nd = node0 + 4 * g + r;
            if (c == 0 && nd < n) { es[nd] = xa; ed_[nd] = ya; }
        }
    }
    // ---- pre-scale by dinv (mol) ----
    if (SCALE) {
        #pragma unroll
        for (int r = 0; r < 4; r++) {
            float dd = dinv[node0 + 4 * g + r];
            #pragma unroll
            for (int t = 0; t < 4; t++) acc[t][r] *= dd;
        }
    }

    // ---- repack through LDS (reuse X1 slab) -> coalesced float4 f16 stores ----
    #pragma unroll
    for (int t = 0; t < 4; t++) {
        #pragma unroll
        for (int r = 0; r < 4; r++)
            X1S[w * 1152 + (4 * g + r) * 72 + 16 * t + c] = __float2half(acc[t][r]);
    }
    __syncthreads();
    int rr = lane >> 2, seg = lane & 3;
    union { f16x8 h; float4 f; } o;
    o.h = *(const f16x8*)&X1S[w * 1152 + rr * 72 + seg * 16];
    int nd = node0 + rr;
    if (!ATT || nd < n)
        *(float4*)&hout[(size_t)nd * 64 + seg * 16] = o.f;
}

__global__ void k_mlp2(const float* __restrict__ aggM, const float* __restrict__ gcn_w1,
                       const float* __restrict__ gcn_b1, const float* __restrict__ gcn_w2,
                       __half* __restrict__ h2hM, const float* __restrict__ dinvM,
                       const float* __restrict__ aggP, const float* __restrict__ gat_w1,
                       const float* __restrict__ gat_b1, const float* __restrict__ gat_w2,
                       const float* __restrict__ as2, const float* __restrict__ ad2,
                       __half* __restrict__ h2hP, float* __restrict__ es, float* __restrict__ ed_){
    __shared__ __attribute__((aligned(16))) __half smemh[14336];   // 28672 B -> 5 blocks/CU
    if (blockIdx.x < NM/64)
        mlp_mfma<6, 0, 1>(smemh, blockIdx.x, threadIdx.x, aggM, gcn_w1, gcn_b1, gcn_w2,
                          nullptr, nullptr, h2hM, nullptr, nullptr, dinvM, NM);
    else
        mlp_mfma<20, 1, 0>(smemh, blockIdx.x - NM/64, threadIdx.x, aggP, gat_w1, gat_b1, gat_w2,
                           as2, ad2, h2hP, es, ed_, nullptr, NP);
}

// ================= merged L2 gathers + fused pooling =================
// prot (25000 blocks): GAT gather -> acc/den, block-reduce 4 nodes -> atomicAdd psumP[bid&63]
// mol  (32768 blocks): GCN gather -> acc*dinv, block-reduce 4 nodes -> atomicAdd gsum[graph]
// biases moved to k_cls (commute with the mean). No molout/protout buffers at all.
__global__ void k_l2g2(const int* __restrict__ protRP, const int* __restrict__ protCOL,
                       const __half* __restrict__ hhP, const float* __restrict__ es,
                       const float* __restrict__ ed_, float* __restrict__ psumP,
                       const int* __restrict__ molRP, const int* __restrict__ molCOL,
                       const __half* __restrict__ hhM, const float* __restrict__ dinv,
                       const int* __restrict__ batch, float* __restrict__ gsum){
    __shared__ float sb[4][64];
    __shared__ int gidS[4];
    int tid = threadIdx.x;
    int wv = tid >> 6, l = tid & 63, g = l >> 3, q = l & 7;
    if (blockIdx.x < NP/4) {
        int node = (blockIdx.x << 2) + wv;
        unsigned pk = (unsigned)protRP[node];
        int s0 = (int)(pk & 0x1FFFFFu);
        int deg = (int)(pk >> 21);
        float edv = ed_[node];
        float selfw = __expf(leaky(es[node] + edv));
        float acc[8] = {0.f,0.f,0.f,0.f,0.f,0.f,0.f,0.f};
        float den = (l == 0) ? selfw : 0.f;
        if (g == 0) {
            H8 r; r.f4 = *(const float4*)&hhP[(size_t)node * 64 + (q << 3)];
            #pragma unroll
            for (int i = 0; i < 4; i++) {
                float2 f = __half22float2(r.h2[i]);
                acc[2*i]     = selfw * f.x;
                acc[2*i + 1] = selfw * f.y;
            }
        }
        for (int base = 0; base < deg; base += 16) {
            int sA = base + g, sB = base + g + 8;
            int cA = protCOL[s0 + sA], cB = protCOL[s0 + sB];
            int uA = (sA < deg) ? cA : node;
            int uB = (sB < deg) ? cB : node;
            float eA = es[uA], eB = es[uB];
            float wA = (sA < deg) ? __expf(leaky(eA + edv)) : 0.f;
            float wB = (sB < deg) ? __expf(leaky(eB + edv)) : 0.f;
            H8 rA, rB;
            rA.f4 = *(const float4*)&hhP[(size_t)uA * 64 + (q << 3)];
            rB.f4 = *(const float4*)&hhP[(size_t)uB * 64 + (q << 3)];
            #pragma unroll
            for (int i = 0; i < 4; i++) {
                float2 fA = __half22float2(rA.h2[i]);
                float2 fB = __half22float2(rB.h2[i]);
                acc[2*i]     += wA * fA.x + wB * fB.x;
                acc[2*i + 1] += wA * fA.y + wB * fB.y;
            }
            if (q == 0) den += wA + wB;
        }
        #pragma unroll
        for (int m = 8; m <= 32; m <<= 1) {
            #pragma unroll
            for (int i = 0; i < 8; i++) acc[i] += __shfl_xor(acc[i], m, 64);
            den += __shfl_xor(den, m, 64);
        }
        den = __shfl(den, 0, 64);
        float sc = 1.f / den;
        if (g == 0) {
            #pragma unroll
            for (int i = 0; i < 8; i++) sb[wv][(q << 3) + i] = acc[i] * sc;
        }
        __syncthreads();
        if (tid < 64) {
            float s = sb[0][tid] + sb[1][tid] + sb[2][tid] + sb[3][tid];
            atomicAdd(&psumP[((blockIdx.x & 63) << 6) + tid], s);
        }
    } else {
        int bid = blockIdx.x - NP/4;
        int node = (bid << 2) + wv;
        unsigned pk = (unsigned)molRP[node];
        int s0 = (int)(pk & 0xFFFFFu);
        int deg = (int)(pk >> 20);
        float acc[8] = {0.f,0.f,0.f,0.f,0.f,0.f,0.f,0.f};
        if (g == 0) {
            H8 r; r.f4 = *(const float4*)&hhM[(size_t)node * 64 + (q << 3)];
            #pragma unroll
            for (int i = 0; i < 4; i++) {
                float2 f = __half22float2(r.h2[i]);
                acc[2*i]     = f.x;
                acc[2*i + 1] = f.y;
            }
        }
        for (int base = 0; base < deg; base += 8) {
            int s = base + g;
            int c = molCOL[s0 + s];
            int u = (s < deg) ? c : node;
            float wvv = (s < deg) ? 1.f : 0.f;
            H8 r; r.f4 = *(const float4*)&hhM[(size_t)u * 64 + (q << 3)];
            #pragma unroll
            for (int i = 0; i < 4; i++) {
                float2 f = __half22float2(r.h2[i]);
                acc[2*i]     += wvv * f.x;
                acc[2*i + 1] += wvv * f.y;
            }
        }
        #pragma unroll
        for (int m = 8; m <= 32; m <<= 1) {
            #pragma unroll
            for (int i = 0; i < 8; i++) acc[i] += __shfl_xor(acc[i], m, 64);
        }
        if (g == 0) {
            float sc = dinv[node];
            #pragma unroll
            for (int i = 0; i < 8; i++) sb[wv][(q << 3) + i] = acc[i] * sc;
        }
        if (l == 0) gidS[wv] = batch[node];
        __syncthreads();
        if (tid < 64) {
            int g0 = gidS[0];
            if (gidS[1] == g0 && gidS[2] == g0 && gidS[3] == g0) {
                float s = sb[0][tid] + sb[1][tid] + sb[2][tid] + sb[3][tid];
                atomicAdd(&gsum[(g0 << 6) + tid], s);
            } else {
                #pragma unroll
                for (int w2 = 0; w2 < 4; w2++)
                    atomicAdd(&gsum[(gidS[w2] << 6) + tid], sb[w2][tid]);
            }
        }
    }
}

// ---------------- fused classifier (now also reduces psumP and applies layer-2 biases) ----------------
__global__ void k_cls(const float* __restrict__ gsum, const int* __restrict__ gstart,
                      const int* __restrict__ gend, const float* __restrict__ psumP,
                      const float* __restrict__ bg, const float* __restrict__ bp,
                      const float* __restrict__ W1, const float* __restrict__ b1,
                      const float* __restrict__ w2, const float* __restrict__ b2,
                      float* __restrict__ out){
    __shared__ float W1s[128 * 64];
    __shared__ float pv[64], bgs[64];
    int tid = threadIdx.x;
    for (int k = tid; k < 128 * 64; k += 256) W1s[k] = W1[k];
    if (tid < 64) {
        float s = 0.f;
        for (int sl = 0; sl < 64; sl++) s += psumP[(sl << 6) + tid];
        pv[tid] = s * (1.0f / (float)NP) + bp[tid];
        bgs[tid] = bg[tid];
    }
    __syncthreads();
    int g = blockIdx.x * 4 + (tid >> 6);
    int j = tid & 63;
    float cntf = (float)(gend[g] - gstart[g]);
    float inv = 1.0f / fmaxf(cntf, 1.0f);
    float acc = b1[j];
    #pragma unroll 8
    for (int k = 0; k < 64; k++) acc += (gsum[g * 64 + k] * inv + bgs[k]) * W1s[k * 64 + j];
    #pragma unroll 8
    for (int k = 0; k < 64; k++) acc += pv[k] * W1s[(64 + k) * 64 + j];
    float v = fmaxf(acc, 0.f) * w2[j];
    #pragma unroll
    for (int off = 32; off > 0; off >>= 1) v += __shfl_down(v, off, 64);
    if (j == 0) out[g] = 1.0f / (1.0f + expf(-(v + b2[0])));
}

extern "C" void kernel_launch(void* const* d_in, const int* in_sizes, int n_in,
                              void* d_out, int out_size, void* d_ws, size_t ws_size,
                              hipStream_t stream) {
    const float* mol_x   = (const float*)d_in[0];
    const int*   mol_ei  = (const int*)d_in[1];
    const int*   mol_bat = (const int*)d_in[2];
    const float* prot_x  = (const float*)d_in[3];
    const int*   prot_ei = (const int*)d_in[4];
    const float* gcn_w1  = (const float*)d_in[5];
    const float* gcn_b1  = (const float*)d_in[6];
    const float* gcn_w2  = (const float*)d_in[7];
    const float* gcn_b2  = (const float*)d_in[8];
    const float* gat_w1  = (const float*)d_in[9];
    const float* gat_as1 = (const float*)d_in[10];
    const float* gat_ad1 = (const float*)d_in[11];
    const float* gat_b1  = (const float*)d_in[12];
    const float* gat_w2  = (const float*)d_in[13];
    const float* gat_as2 = (const float*)d_in[14];
    const float* gat_ad2 = (const float*)d_in[15];
    const float* gat_b2  = (const float*)d_in[16];
    const float* cls_w1  = (const float*)d_in[17];
    const float* cls_b1  = (const float*)d_in[18];
    const float* cls_w2  = (const float*)d_in[19];
    const float* cls_b2  = (const float*)d_in[20];
    float* out = (float*)d_out;

    float* ws_f = (float*)d_ws;

    // ---- persistent tail; [gsum .. psumP+4096) is one contiguous zeroed region ----
    float* T       = ws_f + 16777216;
    float* gsum    = T;                       // 262,144 floats (zeroed; atomic-accumulated)
    int*   gstart  = (int*)(T + 262144);      // 4,096 ints (zeroed)
    int*   gend    = (int*)(T + 266240);      // 4,096 ints (zeroed)
    // T+270336 .. T+270400: legacy psum slot (unused)
    int*   coarseM = (int*)(T + 270400);      // 512 ints (zeroed)
    int*   coarseP = (int*)(T + 270912);      // 512 ints (zeroed)
    int*   cstartM = (int*)(T + 271424);      // 513
    int*   cursorM = (int*)(T + 271937);      // 512
    int*   cstartP = (int*)(T + 272449);      // 513
    int*   cursorP = (int*)(T + 272962);      // 512
    float* psumP   = T + 273474;              // 64 x 64 floats (zeroed; atomic partials)

    // ---- early CSR staging (dead after k_fine2) ----
    unsigned* bufM = (unsigned*)ws_f;                    // [0, 524,288)
    unsigned* bufP = (unsigned*)(ws_f + 524352);         // [524,352, 2,124,416)

    // ---- overlapping phase regions (all offsets in floats) ----
    // [0, 3,200,000):          h2hP (fp16, NP*64) -- written by mlp2, read by l2g2 (prot)
    // [4,194,304, 5,794,304):  x32h (fp16, NP*32) -- dead after l1g2
    // [5,794,304, 7,794,304):  aggP -- dead after mlp2
    // [7,794,304, 7,894,304):  es ; [7,894,304, 7,994,304): ed
    // [8,388,608, 12,582,912): h2hM (fp16, NM*64) -- read by l2g2 (mol)
    __half*   h2hP      = (__half*)ws_f;
    __half*   x32h      = (__half*)(ws_f + 4194304);
    float*    aggP      = ws_f + 5794304;
    float*    es        = ws_f + 7794304;
    float*    ed_       = ws_f + 7894304;
    __half*   h2hM      = (__half*)(ws_f + 8388608);
    int*      molCOL    = (int*)(ws_f + 12582912);       // EM+64 -> 13,107,264
    int*      molRP     = (int*)(ws_f + 13107264);       // NM -> 13,238,336 (+pad)
    float*    dinvM     = ws_f + 13238352;               // NM -> 13,369,424 (+pad)
    __half*   x8h       = (__half*)(ws_f + 13369440);    // NM*8 halves -> 13,893,728 (+pad)
    float*    aggM      = ws_f + 13893792;               // NM*6 -> 14,680,224 (+pad)
    int*      protCOL   = (int*)(ws_f + 14680256);       // EP+64 -> 16,280,320
    int*      protRP    = (int*)(ws_f + 16280320);       // NP -> 16,380,320

    // single upfront zero of gsum+gstart+gend+psum+coarse+cstart/cursor+psumP (contiguous)
    (void)hipMemsetAsync(gsum, 0, (size_t)(273474 + 4096 - 0) * sizeof(float), stream);

    // ================= merged CSR build (mol + prot) =================
    k_hist2<<<256 + 391, 256, 0, stream>>>(mol_ei + EM, prot_ei + EP, coarseM, coarseP);
    k_scan2<<<2, 512, 0, stream>>>(coarseM, cstartM, cursorM, coarseP, cstartP, cursorP);
    k_part2<<<128 + 391, 256, 0, stream>>>(mol_ei, cursorM, bufM, prot_ei, cursorP, bufP);
    k_fine2<<<512 + 391, 256, 0, stream>>>(bufM, cstartM, molRP, molCOL, dinvM,
                                           bufP, cstartP, protRP, protCOL);

    // ================= merged preps =================
    k_prep2<<<512 + 512 + 391, 256, 0, stream>>>(mol_x, dinvM, x8h, mol_bat, gstart, gend,
                                                 prot_x, gat_w1, gat_as1, gat_ad1, x32h, es, ed_);

    // ================= merged L1 gathers (prot: 16 nodes/block) =================
    k_l1g2<<<NM/32 + NP/16, 256, 0, stream>>>(molRP, molCOL, x8h, dinvM, aggM,
                                              protRP, protCOL, x32h, es, ed_, aggP);

    // ================= merged MLPs (MFMA, 64 nodes/block) =================
    k_mlp2<<<NM/64 + cdiv(NP, 64), 256, 0, stream>>>(aggM, gcn_w1, gcn_b1, gcn_w2, h2hM, dinvM,
                                                     aggP, gat_w1, gat_b1, gat_w2, gat_as2, gat_ad2,
                                                     h2hP, es, ed_);

    // ================= merged L2 gathers with fused pooling =================
    k_l2g2<<<NP/4 + NM/4, 256, 0, stream>>>(protRP, protCOL, h2hP, es, ed_, psumP,
                                            molRP, molCOL, h2hM, dinvM, mol_bat, gsum);

    // ================= classifier (reduces psumP, applies layer-2 biases) =================
    k_cls<<<NG/4, 256, 0, stream>>>(gsum, gstart, gend, psumP, gcn_b2, gat_b2,
                                    cls_w1, cls_b1, cls_w2, cls_b2, out);
}

// Round 4
// 331.369 us; speedup vs baseline: 1.2258x; 1.0112x over previous
//
#include <hip/hip_runtime.h>
#include <hip/hip_fp16.h>

#define NM 131072   // mol nodes
#define EM 524288   // mol edges
#define NG 4096     // graphs
#define DM 6        // mol in dim
#define NP 100000   // prot nodes
#define EP 1600000  // prot edges
#define DP 20       // prot in dim

static inline int cdiv(int a, int b){ return (a + b - 1) / b; }

__device__ __forceinline__ float leaky(float x){ return x > 0.f ? x : 0.2f * x; }

union H8 { float4 f4; __half2 h2[4]; };
union HF8 { float4 f4; _Float16 h[8]; };

typedef _Float16 f16x8 __attribute__((ext_vector_type(8)));
typedef float    f32x4 __attribute__((ext_vector_type(4)));

// ================= merged bucketed CSR build (round-16, proven) =================
__global__ void k_hist2(const int* __restrict__ dstM, const int* __restrict__ dstP,
                        int* __restrict__ coarseM, int* __restrict__ coarseP){
    __shared__ int lh[512];
    int t = threadIdx.x;
    const int* dst; int* coarse; int K, E, base, chunk;
    if (blockIdx.x < 256) { dst = dstM; coarse = coarseM; K = 512; E = EM; chunk = 2048; base = blockIdx.x * 2048; }
    else                  { dst = dstP; coarse = coarseP; K = 391; E = EP; chunk = 4096; base = (blockIdx.x - 256) * 4096; }
    for (int i = t; i < K; i += 256) lh[i] = 0;
    __syncthreads();
    int end = min(base + chunk, E);
    for (int e = base + t; e < end; e += 256)
        atomicAdd(&lh[dst[e] >> 8], 1);
    __syncthreads();
    for (int i = t; i < K; i += 256)
        if (lh[i]) atomicAdd(&coarse[i], lh[i]);
}

__global__ void k_scan2(const int* __restrict__ coarseM, int* __restrict__ cstartM, int* __restrict__ cursorM,
                        const int* __restrict__ coarseP, int* __restrict__ cstartP, int* __restrict__ cursorP){
    const int* coarse; int* cstart; int* cursor; int K;
    if (blockIdx.x == 0) { coarse = coarseM; cstart = cstartM; cursor = cursorM; K = 512; }
    else                 { coarse = coarseP; cstart = cstartP; cursor = cursorP; K = 391; }
    int t = threadIdx.x, lane = t & 63, wid = t >> 6;
    int v0 = (t < K) ? coarse[t] : 0;
    int v = v0;
    #pragma unroll
    for (int off = 1; off < 64; off <<= 1) {
        int x = __shfl_up(v, off, 64);
        if (lane >= off) v += x;
    }
    __shared__ int ws[8];
    if (lane == 63) ws[wid] = v;
    __syncthreads();
    int add = 0;
    for (int w = 0; w < wid; w++) add += ws[w];
    int excl = v + add - v0;
    if (t < K) { cstart[t] = excl; cursor[t] = excl; }
    if (t == K - 1) cstart[K] = excl + v0;
}

__global__ void k_part2(const int* __restrict__ eiM, int* __restrict__ cursorM, unsigned* __restrict__ bufM,
                        const int* __restrict__ eiP, int* __restrict__ cursorP, unsigned* __restrict__ bufP){
    __shared__ int lh[512];
    __shared__ int lbase[512];
    const int* ei; int* cursor; unsigned* buf; int E, K, base;
    if (blockIdx.x < 128) { ei = eiM; cursor = cursorM; buf = bufM; E = EM; K = 512; base = blockIdx.x * 4096; }
    else                  { ei = eiP; cursor = cursorP; buf = bufP; E = EP; K = 391; base = (blockIdx.x - 128) * 4096; }
    int t = threadIdx.x;
    for (int i = t; i < K; i += 256) lh[i] = 0;
    __syncthreads();
    int end = min(base + 4096, E);
    unsigned pay[16]; int bslot[16];
    int cnt = 0;
    for (int e = base + t; e < end; e += 256) {
        int u = ei[e], v = ei[E + e];
        int b = v >> 8;
        int ls = atomicAdd(&lh[b], 1);
        pay[cnt] = ((unsigned)(v & 255) << 24) | (unsigned)u;
        bslot[cnt] = (b << 13) | ls;
        cnt++;
    }
    __syncthreads();
    for (int i = t; i < K; i += 256)
        lbase[i] = lh[i] ? atomicAdd(&cursor[i], lh[i]) : 0;
    __syncthreads();
    for (int j = 0; j < cnt; j++) {
        int b = bslot[j] >> 13, ls = bslot[j] & 8191;
        buf[lbase[b] + ls] = pay[j];
    }
}

__global__ void k_fine2(const unsigned* __restrict__ bufM, const int* __restrict__ cstartM,
                        int* __restrict__ molRP, int* __restrict__ molCOL, float* __restrict__ dinv,
                        const unsigned* __restrict__ bufP, const int* __restrict__ cstartP,
                        int* __restrict__ protRP, int* __restrict__ protCOL){
    int t = threadIdx.x;
    int k; const unsigned* buf; const int* cstart; int* rp; int* col; int n, OB, dv;
    if (blockIdx.x < 512) { k = blockIdx.x;       buf = bufM; cstart = cstartM; rp = molRP;  col = molCOL;  n = NM; OB = 20; dv = 1; }
    else                  { k = blockIdx.x - 512; buf = bufP; cstart = cstartP; rp = protRP; col = protCOL; n = NP; OB = 21; dv = 0; }
    int start = cstart[k], end = cstart[k + 1];
    __shared__ int cnt[256];
    __shared__ int cur[256];
    cnt[t] = 0;
    __syncthreads();
    for (int p = start + t; p < end; p += 256)
        atomicAdd(&cnt[buf[p] >> 24], 1);
    __syncthreads();
    int v0 = cnt[t];
    int lane = t & 63, wid = t >> 6;
    int v = v0;
    #pragma unroll
    for (int off = 1; off < 64; off <<= 1) {
        int x = __shfl_up(v, off, 64);
        if (lane >= off) v += x;
    }
    __shared__ int ws[4];
    if (lane == 63) ws[wid] = v;
    __syncthreads();
    int add = 0;
    for (int w = 0; w < wid; w++) add += ws[w];
    int excl = v + add - v0;
    int ofs = start + excl;
    cur[t] = ofs;
    int idx = (k << 8) + t;
    if (idx < n) {
        rp[idx] = (int)((unsigned)ofs | ((unsigned)v0 << OB));
        if (dv) dinv[idx] = rsqrtf((float)(v0 + 1));
    }
    __syncthreads();
    for (int p = start + t; p < end; p += 256) {
        unsigned pk = buf[p];
        int slot = atomicAdd(&cur[pk >> 24], 1);
        col[slot] = (int)(pk & 0xFFFFFFu);
    }
}

// ================= merged prep: molprep (512) + segbounds (512) + prot prep (391) =================
__global__ void k_prep2(const float* __restrict__ mol_x, const float* __restrict__ dinv,
                        __half* __restrict__ x8, const int* __restrict__ batch,
                        int* __restrict__ gstart, int* __restrict__ gend,
                        const float* __restrict__ prot_x, const float* __restrict__ W1,
                        const float* __restrict__ as_, const float* __restrict__ ad_,
                        __half* __restrict__ x32, float* __restrict__ es,
                        float* __restrict__ ed_){
    __shared__ float vas[20], vds[20];
    int b = blockIdx.x, t = threadIdx.x;
    if (b < 512) {
        int i = b * 256 + t;
        float dd = dinv[i];
        H8 r;
        #pragma unroll
        for (int k = 0; k < 3; k++)
            r.h2[k] = __floats2half2_rn(dd * mol_x[i*6 + 2*k], dd * mol_x[i*6 + 2*k + 1]);
        r.h2[3] = __floats2half2_rn(0.f, 0.f);
        *(float4*)&x8[(size_t)i * 8] = r.f4;
    } else if (b < 1024) {
        int i = (b - 512) * 256 + t;
        int g = batch[i];
        if (i == 0 || batch[i - 1] != g) gstart[g] = i;
        if (i == NM - 1 || batch[i + 1] != g) gend[g] = i + 1;
    } else {
        if (t < 20) {
            float s = 0.f;
            for (int j = 0; j < 64; j++) s += W1[t * 64 + j] * as_[j];
            vas[t] = s;
        } else if (t >= 32 && t < 52) {
            int k = t - 32;
            float s = 0.f;
            for (int j = 0; j < 64; j++) s += W1[k * 64 + j] * ad_[j];
            vds[k] = s;
        }
        __syncthreads();
        int i = (b - 1024) * 256 + t;
        if (i >= NP) return;
        float xv[20];
        float s = 0.f, d = 0.f;
        #pragma unroll
        for (int k = 0; k < 20; k++) {
            xv[k] = prot_x[i*20 + k];
            s += xv[k] * vas[k]; d += xv[k] * vds[k];
        }
        es[i] = s; ed_[i] = d;
        H8 r0, r1, r2, rz;
        #pragma unroll
        for (int k = 0; k < 4; k++) r0.h2[k] = __floats2half2_rn(xv[2*k],   xv[2*k+1]);
        #pragma unroll
        for (int k = 0; k < 4; k++) r1.h2[k] = __floats2half2_rn(xv[8+2*k], xv[9+2*k]);
        r2.h2[0] = __floats2half2_rn(xv[16], xv[17]);
        r2.h2[1] = __floats2half2_rn(xv[18], xv[19]);
        r2.h2[2] = __floats2half2_rn(0.f, 0.f);
        r2.h2[3] = __floats2half2_rn(0.f, 0.f);
        rz.h2[0] = rz.h2[1] = rz.h2[2] = rz.h2[3] = __floats2half2_rn(0.f, 0.f);
        *(float4*)&x32[(size_t)i * 32]      = r0.f4;
        *(float4*)&x32[(size_t)i * 32 + 8]  = r1.f4;
        *(float4*)&x32[(size_t)i * 32 + 16] = r2.f4;
        *(float4*)&x32[(size_t)i * 32 + 24] = rz.f4;
    }
}

// ================= merged L1 gathers: mol (4096 blocks) + prot (6250 blocks, 4 nodes/wave) =================
// loads stay unconditional (clamped address, keeps ILP); accumulate predicated + v_fma_mix
__global__ void k_l1g2(const int* __restrict__ molRP, const int* __restrict__ molCOL,
                       const __half* __restrict__ x8, const float* __restrict__ dinv,
                       float* __restrict__ aggM,
                       const int* __restrict__ protRP, const int* __restrict__ protCOL,
                       const __half* __restrict__ x32, const float* __restrict__ es,
                       const float* __restrict__ ed_, float* __restrict__ aggP){
    __shared__ float ost[192];
    int tid = threadIdx.x;
    if (blockIdx.x < NM/32) {
        int bid = blockIdx.x;
        int wv = tid >> 6, l = tid & 63, g = l >> 3, q = l & 7;
        int node = (bid << 5) + (wv << 3) + g;
        unsigned pk = (unsigned)molRP[node];
        int s0 = (int)(pk & 0xFFFFFu);
        int deg = (int)(pk >> 20);
        float acc[6] = {0.f,0.f,0.f,0.f,0.f,0.f};
        if (q == 0) {
            HF8 r; r.f4 = *(const float4*)&x8[(size_t)node * 8];
            #pragma unroll
            for (int i = 0; i < 6; i++) acc[i] = (float)r.h[i];
        }
        for (int base = 0; base < deg; base += 8) {
            int s = base + q;
            int c = molCOL[s0 + s];
            bool vv = s < deg;
            int u = vv ? c : node;
            HF8 r; r.f4 = *(const float4*)&x8[(size_t)u * 8];
            if (vv) {
                #pragma unroll
                for (int i = 0; i < 6; i++) acc[i] += (float)r.h[i];
            }
        }
        #pragma unroll
        for (int m = 1; m < 8; m <<= 1) {
            #pragma unroll
            for (int i = 0; i < 6; i++) acc[i] += __shfl_xor(acc[i], m, 8);
        }
        if (q == 0) {
            float dd = dinv[node];
            int slot = (wv << 3) + g;
            #pragma unroll
            for (int i = 0; i < 6; i++) ost[slot * 6 + i] = dd * acc[i];
        }
        __syncthreads();
        if (tid < 48)
            *(float4*)&aggM[(size_t)bid * 192 + (tid << 2)] = *(float4*)&ost[tid << 2];
    } else {
        // prot: 16 nodes/block, 4 nodes/wave; per node: 4 edge-slots x 4 feature-chunks
        int bid = blockIdx.x - NM/32;
        int wv = tid >> 6, l = tid & 63;
        int nd = l >> 4;          // node within wave
        int slot = (l >> 2) & 3;  // edge slot
        int chunk = l & 3;        // 8-half feature chunk
        int node = (bid << 4) + (wv << 2) + nd;
        unsigned pk = (unsigned)protRP[node];
        int s0 = (int)(pk & 0x1FFFFFu);
        int deg = (int)(pk >> 21);
        float edv = ed_[node];
        float selfw = __expf(leaky(es[node] + edv));
        float acc[8] = {0.f,0.f,0.f,0.f,0.f,0.f,0.f,0.f};
        float den = (slot == 0) ? selfw : 0.f;
        if (slot == 0) {
            HF8 r; r.f4 = *(const float4*)&x32[(size_t)node * 32 + (chunk << 3)];
            #pragma unroll
            for (int i = 0; i < 8; i++) acc[i] = selfw * (float)r.h[i];
        }
        for (int base = 0; base < deg; base += 4) {
            int s = base + slot;
            int c = protCOL[s0 + s];
            bool vv = s < deg;
            int u = vv ? c : node;
            float eu = es[u];
            HF8 r; r.f4 = *(const float4*)&x32[(size_t)u * 32 + (chunk << 3)];
            if (vv) {
                float w = __expf(leaky(eu + edv));
                #pragma unroll
                for (int i = 0; i < 8; i++) acc[i] += w * (float)r.h[i];
                den += w;
            }
        }
        #pragma unroll
        for (int m = 4; m <= 8; m <<= 1) {
            #pragma unroll
            for (int i = 0; i < 8; i++) acc[i] += __shfl_xor(acc[i], m, 64);
            den += __shfl_xor(den, m, 64);
        }
        float inv = 1.f / den;
        if (slot == 0) {
            float4 v0 = make_float4(acc[0]*inv, acc[1]*inv, acc[2]*inv, acc[3]*inv);
            if (chunk < 2) {
                float4 v1 = make_float4(acc[4]*inv, acc[5]*inv, acc[6]*inv, acc[7]*inv);
                *(float4*)&aggP[(size_t)node * 20 + (chunk << 3)]     = v0;
                *(float4*)&aggP[(size_t)node * 20 + (chunk << 3) + 4] = v1;
            } else if (chunk == 2) {
                *(float4*)&aggP[(size_t)node * 20 + 16] = v0;
            }
        }
    }
}

// ================= merged MLP via MFMA (f16 16x16x32), 64 nodes/block, 4 waves =================
// LDS (halves): W1T [64][40] @0, W2T [64][72] @2560, Ain [4][16][40] @7168, X1 [4][16][72] @9728
template<int D, int ATT, int SCALE>
__device__ __forceinline__ void mlp_mfma(__half* smemh, int bid, int tid,
                                         const float* __restrict__ agg, const float* __restrict__ W1,
                                         const float* __restrict__ b1, const float* __restrict__ W2,
                                         const float* __restrict__ as_, const float* __restrict__ ad_,
                                         __half* __restrict__ hout, float* __restrict__ es,
                                         float* __restrict__ ed_, const float* __restrict__ dinv,
                                         int n){
    __half* W1Ts = smemh;            // 64*40 = 2560 halves (k in [32,40) never read)
    __half* W2Ts = smemh + 2560;     // 64*72 = 4608 halves (k in [64,72) never read)
    __half* AinS = smemh + 7168;     // 4 waves * 16 rows * 40 k
    __half* X1S  = smemh + 9728;     // 4 waves * 16 rows * 72 cols
    int lane = tid & 63, w = tid >> 6;
    int c = lane & 15, g = lane >> 4;
    int node0 = bid * 64 + w * 16;

    for (int idx = tid; idx < 2048; idx += 256) {
        int k = idx >> 6, col = idx & 63;
        W1Ts[col * 40 + k] = __float2half(k < D ? W1[k * 64 + col] : 0.f);
    }
    for (int idx = tid; idx < 4096; idx += 256) {
        int k = idx >> 6, col = idx & 63;
        W2Ts[col * 72 + k] = __float2half(W2[k * 64 + col]);
    }
    {
        float4 z4 = make_float4(0.f, 0.f, 0.f, 0.f);
        float4* az = (float4*)(AinS + w * 640);
        for (int i = lane; i < 80; i += 64) az[i] = z4;
        int lim = 16 * D;
        if (ATT) { int rem = n - node0; if (rem < 0) rem = 0; if (rem < 16) lim = rem * D; }
        const float* aw = agg + (size_t)node0 * D;
        for (int idx = lane; idx < lim; idx += 64) {
            int r = idx / D, k = idx - r * D;
            AinS[w * 640 + r * 40 + k] = __float2half(aw[idx]);
        }
    }
    __syncthreads();

    f32x4 zz = {0.f, 0.f, 0.f, 0.f};
    f16x8 a1 = *(const f16x8*)&AinS[w * 640 + c * 40 + 8 * g];
    #pragma unroll
    for (int t = 0; t < 4; t++) {
        f16x8 b = *(const f16x8*)&W1Ts[(16 * t + c) * 40 + 8 * g];
        f32x4 h = __builtin_amdgcn_mfma_f32_16x16x32_f16(a1, b, zz, 0, 0, 0);
        float bv = b1[16 * t + c];
        #pragma unroll
        for (int r = 0; r < 4; r++) {
            float v = fmaxf(h[r] + bv, 0.f);
            X1S[w * 1152 + (4 * g + r) * 72 + 16 * t + c] = __float2half(v);
        }
    }
    __syncthreads();

    f32x4 acc[4];
    #pragma unroll
    for (int t = 0; t < 4; t++) acc[t] = zz;
    #pragma unroll
    for (int kt = 0; kt < 2; kt++) {
        f16x8 a = *(const f16x8*)&X1S[w * 1152 + c * 72 + 32 * kt + 8 * g];
        #pragma unroll
        for (int t = 0; t < 4; t++) {
            f16x8 b = *(const f16x8*)&W2Ts[(16 * t + c) * 72 + 32 * kt + 8 * g];
            acc[t] = __builtin_amdgcn_mfma_f32_16x16x32_f16(a, b, acc[t], 0, 0, 0);
        }
    }

    if (ATT) {
        float asv[4], adv[4];
        #pragma unroll
        for (int t = 0; t < 4; t++) { asv[t] = as_[16 * t + c]; adv[t] = ad_[16 * t + c]; }
        #pragma unroll
        for (int r = 0; r < 4; r++) {
            float xa = 0.f, ya = 0.f;
            #pragma unroll
            for (int t = 0; t < 4; t++) { xa += acc[t][r] * asv[t]; ya += acc[t][r] * adv[t]; }
            #pragma unroll
            for (int m = 1; m < 16; m <<= 1) { xa += __shfl_xor(xa, m, 16); ya += __shfl_xor(ya, m, 16); }
            int nd = node0 + 4 * g + r;
            if (c == 0 && nd < n) { es[nd] = xa; ed_[nd] = ya; }
        }
    }
    if (SCALE) {
        #pragma unroll
        for (int r = 0; r < 4; r++) {
            float dd = dinv[node0 + 4 * g + r];
            #pragma unroll
            for (int t = 0; t < 4; t++) acc[t][r] *= dd;
        }
    }

    #pragma unroll
    for (int t = 0; t < 4; t++) {
        #pragma unroll
        for (int r = 0; r < 4; r++)
            X1S[w * 1152 + (4 * g + r) * 72 + 16 * t + c] = __float2half(acc[t][r]);
    }
    __syncthreads();
    int rr = lane >> 2, seg = lane & 3;
    union { f16x8 h; float4 f; } o;
    o.h = *(const f16x8*)&X1S[w * 1152 + rr * 72 + seg * 16];
    int nd = node0 + rr;
    if (!ATT || nd < n)
        *(float4*)&hout[(size_t)nd * 64 + seg * 16] = o.f;
}

__global__ void k_mlp2(const float* __restrict__ aggM, const float* __restrict__ gcn_w1,
                       const float* __restrict__ gcn_b1, const float* __restrict__ gcn_w2,
                       __half* __restrict__ h2hM, const float* __restrict__ dinvM,
                       const float* __restrict__ aggP, const float* __restrict__ gat_w1,
                       const float* __restrict__ gat_b1, const float* __restrict__ gat_w2,
                       const float* __restrict__ as2, const float* __restrict__ ad2,
                       __half* __restrict__ h2hP, float* __restrict__ es, float* __restrict__ ed_){
    __shared__ __attribute__((aligned(16))) __half smemh[14336];   // 28672 B -> 5 blocks/CU
    if (blockIdx.x < NM/64)
        mlp_mfma<6, 0, 1>(smemh, blockIdx.x, threadIdx.x, aggM, gcn_w1, gcn_b1, gcn_w2,
                          nullptr, nullptr, h2hM, nullptr, nullptr, dinvM, NM);
    else
        mlp_mfma<20, 1, 0>(smemh, blockIdx.x - NM/64, threadIdx.x, aggP, gat_w1, gat_b1, gat_w2,
                           as2, ad2, h2hP, es, ed_, nullptr, NP);
}

// ================= merged L2 gathers + fused pooling =================
// loads stay unconditional (clamped address, keeps ILP); accumulate predicated + v_fma_mix
__global__ void k_l2g2(const int* __restrict__ protRP, const int* __restrict__ protCOL,
                       const __half* __restrict__ hhP, const float* __restrict__ es,
                       const float* __restrict__ ed_, float* __restrict__ psumP,
                       const int* __restrict__ molRP, const int* __restrict__ molCOL,
                       const __half* __restrict__ hhM, const float* __restrict__ dinv,
                       const int* __restrict__ batch, float* __restrict__ gsum){
    __shared__ float sb[4][64];
    __shared__ int gidS[4];
    int tid = threadIdx.x;
    int wv = tid >> 6, l = tid & 63, g = l >> 3, q = l & 7;
    if (blockIdx.x < NP/4) {
        int node = (blockIdx.x << 2) + wv;
        unsigned pk = (unsigned)protRP[node];
        int s0 = (int)(pk & 0x1FFFFFu);
        int deg = (int)(pk >> 21);
        float edv = ed_[node];
        float selfw = __expf(leaky(es[node] + edv));
        float acc[8] = {0.f,0.f,0.f,0.f,0.f,0.f,0.f,0.f};
        float den = (l == 0) ? selfw : 0.f;
        if (g == 0) {
            HF8 r; r.f4 = *(const float4*)&hhP[(size_t)node * 64 + (q << 3)];
            #pragma unroll
            for (int i = 0; i < 8; i++) acc[i] = selfw * (float)r.h[i];
        }
        for (int base = 0; base < deg; base += 16) {
            int sA = base + g, sB = base + g + 8;
            int cA = protCOL[s0 + sA], cB = protCOL[s0 + sB];
            bool vA = sA < deg, vB = sB < deg;
            int uA = vA ? cA : node;
            int uB = vB ? cB : node;
            float eA = es[uA], eB = es[uB];
            HF8 rA, rB;
            rA.f4 = *(const float4*)&hhP[(size_t)uA * 64 + (q << 3)];
            rB.f4 = *(const float4*)&hhP[(size_t)uB * 64 + (q << 3)];
            if (vA) {
                float wA = __expf(leaky(eA + edv));
                #pragma unroll
                for (int i = 0; i < 8; i++) acc[i] += wA * (float)rA.h[i];
                if (q == 0) den += wA;
            }
            if (vB) {
                float wB = __expf(leaky(eB + edv));
                #pragma unroll
                for (int i = 0; i < 8; i++) acc[i] += wB * (float)rB.h[i];
                if (q == 0) den += wB;
            }
        }
        #pragma unroll
        for (int m = 8; m <= 32; m <<= 1) {
            #pragma unroll
            for (int i = 0; i < 8; i++) acc[i] += __shfl_xor(acc[i], m, 64);
            den += __shfl_xor(den, m, 64);
        }
        den = __shfl(den, 0, 64);
        float sc = 1.f / den;
        if (g == 0) {
            #pragma unroll
            for (int i = 0; i < 8; i++) sb[wv][(q << 3) + i] = acc[i] * sc;
        }
        __syncthreads();
        if (tid < 64) {
            float s = sb[0][tid] + sb[1][tid] + sb[2][tid] + sb[3][tid];
            atomicAdd(&psumP[((blockIdx.x & 63) << 6) + tid], s);
        }
    } else {
        int bid = blockIdx.x - NP/4;
        int node = (bid << 2) + wv;
        unsigned pk = (unsigned)molRP[node];
        int s0 = (int)(pk & 0xFFFFFu);
        int deg = (int)(pk >> 20);
        float acc[8] = {0.f,0.f,0.f,0.f,0.f,0.f,0.f,0.f};
        if (g == 0) {
            HF8 r; r.f4 = *(const float4*)&hhM[(size_t)node * 64 + (q << 3)];
            #pragma unroll
            for (int i = 0; i < 8; i++) acc[i] = (float)r.h[i];
        }
        for (int base = 0; base < deg; base += 8) {
            int s = base + g;
            int c = molCOL[s0 + s];
            bool vv = s < deg;
            int u = vv ? c : node;
            HF8 r; r.f4 = *(const float4*)&hhM[(size_t)u * 64 + (q << 3)];
            if (vv) {
                #pragma unroll
                for (int i = 0; i < 8; i++) acc[i] += (float)r.h[i];
            }
        }
        #pragma unroll
        for (int m = 8; m <= 32; m <<= 1) {
            #pragma unroll
            for (int i = 0; i < 8; i++) acc[i] += __shfl_xor(acc[i], m, 64);
        }
        if (g == 0) {
            float sc = dinv[node];
            #pragma unroll
            for (int i = 0; i < 8; i++) sb[wv][(q << 3) + i] = acc[i] * sc;
        }
        if (l == 0) gidS[wv] = batch[node];
        __syncthreads();
        if (tid < 64) {
            int g0 = gidS[0];
            if (gidS[1] == g0 && gidS[2] == g0 && gidS[3] == g0) {
                float s = sb[0][tid] + sb[1][tid] + sb[2][tid] + sb[3][tid];
                atomicAdd(&gsum[(g0 << 6) + tid], s);
            } else {
                #pragma unroll
                for (int w2 = 0; w2 < 4; w2++)
                    atomicAdd(&gsum[(gidS[w2] << 6) + tid], sb[w2][tid]);
            }
        }
    }
}

// ---------------- fused classifier (reduces psumP, applies layer-2 biases) ----------------
__global__ void k_cls(const float* __restrict__ gsum, const int* __restrict__ gstart,
                      const int* __restrict__ gend, const float* __restrict__ psumP,
                      const float* __restrict__ bg, const float* __restrict__ bp,
                      const float* __restrict__ W1, const float* __restrict__ b1,
                      const float* __restrict__ w2, const float* __restrict__ b2,
                      float* __restrict__ out){
    __shared__ float W1s[128 * 64];
    __shared__ float pv[64], bgs[64];
    int tid = threadIdx.x;
    for (int k = tid; k < 128 * 64; k += 256) W1s[k] = W1[k];
    if (tid < 64) {
        float s = 0.f;
        for (int sl = 0; sl < 64; sl++) s += psumP[(sl << 6) + tid];
        pv[tid] = s * (1.0f / (float)NP) + bp[tid];
        bgs[tid] = bg[tid];
    }
    __syncthreads();
    int g = blockIdx.x * 4 + (tid >> 6);
    int j = tid & 63;
    float cntf = (float)(gend[g] - gstart[g]);
    float inv = 1.0f / fmaxf(cntf, 1.0f);
    float acc = b1[j];
    #pragma unroll 8
    for (int k = 0; k < 64; k++) acc += (gsum[g * 64 + k] * inv + bgs[k]) * W1s[k * 64 + j];
    #pragma unroll 8
    for (int k = 0; k < 64; k++) acc += pv[k] * W1s[(64 + k) * 64 + j];
    float v = fmaxf(acc, 0.f) * w2[j];
    #pragma unroll
    for (int off = 32; off > 0; off >>= 1) v += __shfl_down(v, off, 64);
    if (j == 0) out[g] = 1.0f / (1.0f + expf(-(v + b2[0])));
}

extern "C" void kernel_launch(void* const* d_in, const int* in_sizes, int n_in,
                              void* d_out, int out_size, void* d_ws, size_t ws_size,
                              hipStream_t stream) {
    const float* mol_x   = (const float*)d_in[0];
    const int*   mol_ei  = (const int*)d_in[1];
    const int*   mol_bat = (const int*)d_in[2];
    const float* prot_x  = (const float*)d_in[3];
    const int*   prot_ei = (const int*)d_in[4];
    const float* gcn_w1  = (const float*)d_in[5];
    const float* gcn_b1  = (const float*)d_in[6];
    const float* gcn_w2  = (const float*)d_in[7];
    const float* gcn_b2  = (const float*)d_in[8];
    const float* gat_w1  = (const float*)d_in[9];
    const float* gat_as1 = (const float*)d_in[10];
    const float* gat_ad1 = (const float*)d_in[11];
    const float* gat_b1  = (const float*)d_in[12];
    const float* gat_w2  = (const float*)d_in[13];
    const float* gat_as2 = (const float*)d_in[14];
    const float* gat_ad2 = (const float*)d_in[15];
    const float* gat_b2  = (const float*)d_in[16];
    const float* cls_w1  = (const float*)d_in[17];
    const float* cls_b1  = (const float*)d_in[18];
    const float* cls_w2  = (const float*)d_in[19];
    const float* cls_b2  = (const float*)d_in[20];
    float* out = (float*)d_out;

    float* ws_f = (float*)d_ws;

    // ---- persistent tail ----
    float* T       = ws_f + 16777216;
    float* gsum    = T;                       // 262,144 floats (zeroed; atomic-accumulated)
    int*   gstart  = (int*)(T + 262144);      // 4,096 ints (zeroed)
    int*   gend    = (int*)(T + 266240);      // 4,096 ints (zeroed)
    int*   coarseM = (int*)(T + 270400);      // 512 ints (zeroed)
    int*   coarseP = (int*)(T + 270912);      // 512 ints (zeroed)
    int*   cstartM = (int*)(T + 271424);      // 513
    int*   cursorM = (int*)(T + 271937);      // 512
    int*   cstartP = (int*)(T + 272449);      // 513
    int*   cursorP = (int*)(T + 272962);      // 512
    float* psumP   = T + 273474;              // 64 x 64 floats (zeroed; atomic partials)

    // ---- early CSR staging (dead after k_fine2) ----
    unsigned* bufM = (unsigned*)ws_f;                    // [0, 524,288)
    unsigned* bufP = (unsigned*)(ws_f + 524352);         // [524,352, 2,124,416)

    // ---- overlapping phase regions (all offsets in floats) ----
    __half*   h2hP      = (__half*)ws_f;
    __half*   x32h      = (__half*)(ws_f + 4194304);
    float*    aggP      = ws_f + 5794304;
    float*    es        = ws_f + 7794304;
    float*    ed_       = ws_f + 7894304;
    __half*   h2hM      = (__half*)(ws_f + 8388608);
    int*      molCOL    = (int*)(ws_f + 12582912);       // EM+64 -> 13,107,264
    int*      molRP     = (int*)(ws_f + 13107264);       // NM -> 13,238,336 (+pad)
    float*    dinvM     = ws_f + 13238352;               // NM -> 13,369,424 (+pad)
    __half*   x8h       = (__half*)(ws_f + 13369440);    // NM*8 halves -> 13,893,728 (+pad)
    float*    aggM      = ws_f + 13893792;               // NM*6 -> 14,680,224 (+pad)
    int*      protCOL   = (int*)(ws_f + 14680256);       // EP+64 -> 16,280,320
    int*      protRP    = (int*)(ws_f + 16280320);       // NP -> 16,380,320

    // single upfront zero of gsum..psumP (contiguous)
    (void)hipMemsetAsync(gsum, 0, (size_t)(273474 + 4096) * sizeof(float), stream);

    // ================= merged CSR build (mol + prot) =================
    k_hist2<<<256 + 391, 256, 0, stream>>>(mol_ei + EM, prot_ei + EP, coarseM, coarseP);
    k_scan2<<<2, 512, 0, stream>>>(coarseM, cstartM, cursorM, coarseP, cstartP, cursorP);
    k_part2<<<128 + 391, 256, 0, stream>>>(mol_ei, cursorM, bufM, prot_ei, cursorP, bufP);
    k_fine2<<<512 + 391, 256, 0, stream>>>(bufM, cstartM, molRP, molCOL, dinvM,
                                           bufP, cstartP, protRP, protCOL);

    // ================= merged preps =================
    k_prep2<<<512 + 512 + 391, 256, 0, stream>>>(mol_x, dinvM, x8h, mol_bat, gstart, gend,
                                                 prot_x, gat_w1, gat_as1, gat_ad1, x32h, es, ed_);

    // ================= merged L1 gathers (prot: 16 nodes/block) =================
    k_l1g2<<<NM/32 + NP/16, 256, 0, stream>>>(molRP, molCOL, x8h, dinvM, aggM,
                                              protRP, protCOL, x32h, es, ed_, aggP);

    // ================= merged MLPs (MFMA, 64 nodes/block) =================
    k_mlp2<<<NM/64 + cdiv(NP, 64), 256, 0, stream>>>(aggM, gcn_w1, gcn_b1, gcn_w2, h2hM, dinvM,
                                                     aggP, gat_w1, gat_b1, gat_w2, gat_as2, gat_ad2,
                                                     h2hP, es, ed_);

    // ================= merged L2 gathers with fused pooling =================
    k_l2g2<<<NP/4 + NM/4, 256, 0, stream>>>(protRP, protCOL, h2hP, es, ed_, psumP,
                                            molRP, molCOL, h2hM, dinvM, mol_bat, gsum);

    // ================= classifier (reduces psumP, applies layer-2 biases) =================
    k_cls<<<NG/4, 256, 0, stream>>>(gsum, gstart, gend, psumP, gcn_b2, gat_b2,
                                    cls_w1, cls_b1, cls_w2, cls_b2, out);
}